// Round 1
// baseline (2802.921 us; speedup 1.0000x reference)
//
#include <hip/hip_runtime.h>
#include <cstddef>

// ---- problem constants ----
#define DD   256
#define NHH  8
#define HDD  32
#define BB   8
#define LT   32
#define LV   8500   // 6400+1600+400+100

__device__ __forceinline__ float gelu_f(float x) {
  // jax.nn.gelu approximate=False: x * 0.5 * (1 + erf(x/sqrt(2)))
  return 0.5f * x * (1.0f + erff(x * 0.70710678118654752440f));
}

enum { AM_PLAIN = 0, AM_ADD = 1, AM_FEAT = 2 };
enum { EP_BIAS = 0, EP_GELU = 1, EP_ACC = 2 };

// Generic fp32 tiled GEMM: C[M x N] = op_epi( A[M x K] @ W[K x N] + bias )
// A-modes: PLAIN (A0), ADD (A0 + A1), FEAT (gather value matrix from [B,D,HW] feats).
// N is implied by gridDim.y * BN (all our Ns are multiples of BN, no col guard).
// lda == K for all callers.
template<int BM, int BN, int TM, int TN, int AMODE, int EPI>
__launch_bounds__(256)
__global__ void gemm_k(const float* __restrict__ A0, const float* __restrict__ A1,
                       const float* __restrict__ Wt, const float* __restrict__ bias,
                       float* __restrict__ C, int M, int K, int ldw, int ldc,
                       const float* __restrict__ f0, const float* __restrict__ f1,
                       const float* __restrict__ f2, const float* __restrict__ f3)
{
  constexpr int BK = 16;
  __shared__ __align__(16) float As[BK][BM];
  __shared__ __align__(16) float Ws[BK][BN];
  const int tid  = threadIdx.x;
  const int row0 = blockIdx.x * BM;
  const int col0 = blockIdx.y * BN;
  const int tx = tid % (BN / TN);
  const int ty = tid / (BN / TN);
  float acc[TM][TN] = {};

  for (int k0 = 0; k0 < K; k0 += BK) {
    if constexpr (AMODE == AM_FEAT) {
      // value[b, s, k] = feat_l[b, k, s - start_l]; load float4 along spatial s.
      constexpr int AU = BM * BK / 4;
      for (int u = tid; u < AU; u += 256) {
        int k  = u / (BM / 4);
        int m4 = (u % (BM / 4)) * 4;
        int grow = row0 + m4;
        float4 v = make_float4(0.f, 0.f, 0.f, 0.f);
        if (grow < M) {
          int b = grow / LV;
          int s = grow - b * LV;
          int l = (s >= 8400) ? 3 : (s >= 8000) ? 2 : (s >= 6400) ? 1 : 0;
          const float* fp = (l == 0) ? f0 : (l == 1) ? f1 : (l == 2) ? f2 : f3;
          const int hw = (l == 0) ? 6400 : (l == 1) ? 1600 : (l == 2) ? 400 : 100;
          const int st = (l == 0) ? 0 : (l == 1) ? 6400 : (l == 2) ? 8000 : 8400;
          v = *(const float4*)(fp + ((size_t)b * DD + (k0 + k)) * hw + (s - st));
        }
        *(float4*)&As[k][m4] = v;
      }
    } else {
      constexpr int AU = BM * BK / 4;
      for (int u = tid; u < AU; u += 256) {
        int m  = u / (BK / 4);
        int kq = (u % (BK / 4)) * 4;
        int grow = row0 + m;
        float4 v = make_float4(0.f, 0.f, 0.f, 0.f);
        if (grow < M) {
          v = *(const float4*)(A0 + (size_t)grow * K + k0 + kq);
          if constexpr (AMODE == AM_ADD) {
            float4 w = *(const float4*)(A1 + (size_t)grow * K + k0 + kq);
            v.x += w.x; v.y += w.y; v.z += w.z; v.w += w.w;
          }
        }
        As[kq + 0][m] = v.x; As[kq + 1][m] = v.y;
        As[kq + 2][m] = v.z; As[kq + 3][m] = v.w;
      }
    }
    {
      constexpr int WU = BK * BN / 4;
      for (int u = tid; u < WU; u += 256) {
        int k  = u / (BN / 4);
        int n4 = (u % (BN / 4)) * 4;
        *(float4*)&Ws[k][n4] =
            *(const float4*)(Wt + (size_t)(k0 + k) * ldw + col0 + n4);
      }
    }
    __syncthreads();

    #pragma unroll
    for (int k = 0; k < BK; ++k) {
      float a[TM], bv[TN];
      if constexpr (TM % 4 == 0) {
        #pragma unroll
        for (int i = 0; i < TM; i += 4) {
          float4 t4 = *(const float4*)&As[k][ty * TM + i];
          a[i] = t4.x; a[i + 1] = t4.y; a[i + 2] = t4.z; a[i + 3] = t4.w;
        }
      } else {
        #pragma unroll
        for (int i = 0; i < TM; ++i) a[i] = As[k][ty * TM + i];
      }
      #pragma unroll
      for (int j = 0; j < TN; j += 4) {
        float4 t4 = *(const float4*)&Ws[k][tx * TN + j];
        bv[j] = t4.x; bv[j + 1] = t4.y; bv[j + 2] = t4.z; bv[j + 3] = t4.w;
      }
      #pragma unroll
      for (int i = 0; i < TM; ++i)
        #pragma unroll
        for (int j = 0; j < TN; ++j)
          acc[i][j] = fmaf(a[i], bv[j], acc[i][j]);
    }
    __syncthreads();
  }

  #pragma unroll
  for (int i = 0; i < TM; ++i) {
    int r = row0 + ty * TM + i;
    if (r >= M) continue;
    #pragma unroll
    for (int j4 = 0; j4 < TN; j4 += 4) {
      int c = col0 + tx * TN + j4;
      float4 v = make_float4(acc[i][j4], acc[i][j4 + 1], acc[i][j4 + 2], acc[i][j4 + 3]);
      if constexpr (EPI == EP_ACC) {
        float4 old = *(const float4*)(C + (size_t)r * ldc + c);
        v.x += old.x; v.y += old.y; v.z += old.z; v.w += old.w;
      } else {
        float4 b4 = *(const float4*)(bias + c);
        v.x += b4.x; v.y += b4.y; v.z += b4.z; v.w += b4.w;
        if constexpr (EPI == EP_GELU) {
          v.x = gelu_f(v.x); v.y = gelu_f(v.y); v.z = gelu_f(v.z); v.w = gelu_f(v.w);
        }
      }
      *(float4*)(C + (size_t)r * ldc + c) = v;
    }
  }
}

// LayerNorm over D=256 with fused residual: O[row] = LN(X[row] + R[row]) * g + b
// One 64-lane wave per row, 4 rows per 256-thread block.
__global__ void ln_kernel(const float* __restrict__ X, const float* __restrict__ R,
                          const float* __restrict__ g, const float* __restrict__ bta,
                          float* __restrict__ O, int M)
{
  int row  = blockIdx.x * 4 + (threadIdx.x >> 6);
  int lane = threadIdx.x & 63;
  if (row >= M) return;
  size_t base = (size_t)row * DD + lane * 4;
  float4 x = *(const float4*)(X + base);
  float4 r = *(const float4*)(R + base);
  x.x += r.x; x.y += r.y; x.z += r.z; x.w += r.w;
  float s  = x.x + x.y + x.z + x.w;
  float s2 = x.x * x.x + x.y * x.y + x.z * x.z + x.w * x.w;
  #pragma unroll
  for (int m = 1; m < 64; m <<= 1) {
    s  += __shfl_xor(s, m);
    s2 += __shfl_xor(s2, m);
  }
  float mean = s * (1.0f / 256.0f);
  float var  = s2 * (1.0f / 256.0f) - mean * mean;
  float rstd = rsqrtf(var + 1e-5f);
  float4 gg = *(const float4*)(g + lane * 4);
  float4 bb = *(const float4*)(bta + lane * 4);
  float4 o;
  o.x = (x.x - mean) * rstd * gg.x + bb.x;
  o.y = (x.y - mean) * rstd * gg.y + bb.y;
  o.z = (x.z - mean) * rstd * gg.z + bb.z;
  o.w = (x.w - mean) * rstd * gg.w + bb.w;
  *(float4*)(O + base) = o;
}

// Per (b,q,h): softmax over NL*NP=16 attention logits; sampling locations
// loc = ref + off / (W_l, H_l). Layouts: awl [row,128] col=h*16+(l*4+p);
// offb/loc [row,256] col = h*32 + l*8 + p*2 + c; refp [row,4,2].
__global__ void softloc_kernel(const float* __restrict__ awl, const float* __restrict__ offb,
                               const float* __restrict__ refp, float* __restrict__ aw,
                               float* __restrict__ loc)
{
  int idx = blockIdx.x * 256 + threadIdx.x;
  if (idx >= BB * LT * NHH) return;
  int h   = idx & 7;
  int row = idx >> 3;
  float v[16]; float mx = -1e30f;
  #pragma unroll
  for (int i = 0; i < 16; ++i) { v[i] = awl[row * 128 + h * 16 + i]; mx = fmaxf(mx, v[i]); }
  float sum = 0.f;
  #pragma unroll
  for (int i = 0; i < 16; ++i) { v[i] = expf(v[i] - mx); sum += v[i]; }
  float inv = 1.0f / sum;
  #pragma unroll
  for (int i = 0; i < 16; ++i) aw[row * 128 + h * 16 + i] = v[i] * inv;
  const float invn[4] = {1.f / 80.f, 1.f / 40.f, 1.f / 20.f, 1.f / 10.f};
  #pragma unroll
  for (int l = 0; l < 4; ++l) {
    float rx = refp[(row * 4 + l) * 2 + 0];
    float ry = refp[(row * 4 + l) * 2 + 1];
    #pragma unroll
    for (int p = 0; p < 4; ++p) {
      int o = row * 256 + h * 32 + l * 8 + p * 2;
      loc[o + 0] = rx + offb[o + 0] * invn[l];
      loc[o + 1] = ry + offb[o + 1] * invn[l];
    }
  }
}

// Deformable sampling: one block per (b,q); thread = (h, hd).
// acc[row, h*32+hd] = sum_{l,p,corners} aw * w_bilinear * vproj[b, start_l+pos, h*32+hd]
__global__ void sampler_kernel(const float* __restrict__ vproj, const float* __restrict__ loc,
                               const float* __restrict__ aw, float* __restrict__ acc)
{
  int row = blockIdx.x;          // b*32 + q
  int t   = threadIdx.x;
  int h   = t >> 5, hd = t & 31;
  int b   = row >> 5;
  const float* vb = vproj + (size_t)b * LV * DD;
  const int Hs[4] = {80, 40, 20, 10};
  const int st[4] = {0, 6400, 8000, 8400};
  float a = 0.f;
  #pragma unroll
  for (int l = 0; l < 4; ++l) {
    const int Wl = Hs[l], Hl = Hs[l];   // square levels
    #pragma unroll
    for (int p = 0; p < 4; ++p) {
      int o = row * 256 + h * 32 + l * 8 + p * 2;
      float lx  = loc[o + 0];
      float ly  = loc[o + 1];
      float wgt = aw[row * 128 + h * 16 + l * 4 + p];
      float x = lx * (float)Wl - 0.5f;
      float y = ly * (float)Hl - 0.5f;
      float x0f = floorf(x), y0f = floorf(y);
      float fx = x - x0f, fy = y - y0f;
      int x0 = (int)x0f, y0 = (int)y0f;
      #pragma unroll
      for (int dy = 0; dy < 2; ++dy) {
        #pragma unroll
        for (int dx = 0; dx < 2; ++dx) {
          int xi = x0 + dx, yi = y0 + dy;
          float w = (dx ? fx : 1.f - fx) * (dy ? fy : 1.f - fy);
          if (xi >= 0 && xi < Wl && yi >= 0 && yi < Hl) {
            a = fmaf(wgt * w, vb[(size_t)(st[l] + yi * Wl + xi) * DD + h * 32 + hd], a);
          }
        }
      }
    }
  }
  acc[(size_t)row * DD + t] = a;
}

// Cross attention (32 keys, HD=32): 8 threads per vis query row (one per head).
// Writes mo [row,256] and head-mean attention weights [row,32].
__global__ void attn_kernel(const float* __restrict__ qh, const float* __restrict__ kh,
                            const float* __restrict__ vh, float* __restrict__ mo,
                            float* __restrict__ awout)
{
  int t  = threadIdx.x;
  int rl = t >> 3, h = t & 7;
  int row = blockIdx.x * 32 + rl;
  if (row >= BB * LV) return;       // grid is exact (68000 = 32*2125); kept for safety
  int b = row / LV;
  const float scale = 0.17677669529663687f;  // 1/sqrt(32)
  float q[32];
  {
    const float4* qp = (const float4*)(qh + (size_t)row * DD + h * 32);
    #pragma unroll
    for (int i = 0; i < 8; ++i) {
      float4 v = qp[i];
      q[i * 4] = v.x; q[i * 4 + 1] = v.y; q[i * 4 + 2] = v.z; q[i * 4 + 3] = v.w;
    }
  }
  float s[32]; float mx = -1e30f;
  #pragma unroll
  for (int k = 0; k < 32; ++k) {
    const float4* kp = (const float4*)(kh + (size_t)(b * 32 + k) * DD + h * 32);
    float d = 0.f;
    #pragma unroll
    for (int i = 0; i < 8; ++i) {
      float4 v = kp[i];
      d = fmaf(q[i * 4], v.x, d); d = fmaf(q[i * 4 + 1], v.y, d);
      d = fmaf(q[i * 4 + 2], v.z, d); d = fmaf(q[i * 4 + 3], v.w, d);
    }
    s[k] = d * scale;
    mx = fmaxf(mx, s[k]);
  }
  float sum = 0.f;
  #pragma unroll
  for (int k = 0; k < 32; ++k) { s[k] = expf(s[k] - mx); sum += s[k]; }
  float inv = 1.0f / sum;
  #pragma unroll
  for (int k = 0; k < 32; ++k) s[k] *= inv;
  float o[32] = {};
  #pragma unroll
  for (int k = 0; k < 32; ++k) {
    const float4* vp = (const float4*)(vh + (size_t)(b * 32 + k) * DD + h * 32);
    float pk = s[k];
    #pragma unroll
    for (int i = 0; i < 8; ++i) {
      float4 v = vp[i];
      o[i * 4] = fmaf(pk, v.x, o[i * 4]);       o[i * 4 + 1] = fmaf(pk, v.y, o[i * 4 + 1]);
      o[i * 4 + 2] = fmaf(pk, v.z, o[i * 4 + 2]); o[i * 4 + 3] = fmaf(pk, v.w, o[i * 4 + 3]);
    }
  }
  {
    float4* op = (float4*)(mo + (size_t)row * DD + h * 32);
    #pragma unroll
    for (int i = 0; i < 8; ++i)
      op[i] = make_float4(o[i * 4], o[i * 4 + 1], o[i * 4 + 2], o[i * 4 + 3]);
  }
  // head-mean of p: reduce over the 3 head bits (lanes r*8 .. r*8+7 share a wave)
  #pragma unroll
  for (int k = 0; k < 32; ++k) {
    float v = s[k];
    v += __shfl_xor(v, 1);
    v += __shfl_xor(v, 2);
    v += __shfl_xor(v, 4);
    if (h == 0) awout[(size_t)row * 32 + k] = v * 0.125f;
  }
}

extern "C" void kernel_launch(void* const* d_in, const int* in_sizes, int n_in,
                              void* d_out, int out_size, void* d_ws, size_t ws_size,
                              hipStream_t stream)
{
  const float* txt_tokens = (const float*)d_in[0];
  const float* vis_tokens = (const float*)d_in[1];
  const float* feat0 = (const float*)d_in[2];
  const float* feat1 = (const float*)d_in[3];
  const float* feat2 = (const float*)d_in[4];
  const float* feat3 = (const float*)d_in[5];
  // d_in[6] spatial_shapes, d_in[7] level_start_index — compile-time constants here
  const float* refp    = (const float*)d_in[8];
  const float* txt_pos = (const float*)d_in[9];
  const float* vis_pos = (const float*)d_in[10];
  const float* W_off = (const float*)d_in[11]; const float* b_off = (const float*)d_in[12];
  const float* W_aw  = (const float*)d_in[13]; const float* b_aw  = (const float*)d_in[14];
  const float* W_v   = (const float*)d_in[15]; const float* b_v   = (const float*)d_in[16];
  const float* W_do  = (const float*)d_in[17]; const float* b_do  = (const float*)d_in[18];
  const float* W_q   = (const float*)d_in[19]; const float* b_q   = (const float*)d_in[20];
  const float* W_out = (const float*)d_in[21]; const float* b_out = (const float*)d_in[22];
  const float* ln1_g = (const float*)d_in[23]; const float* ln1_b = (const float*)d_in[24];
  const float* ln2_g = (const float*)d_in[25]; const float* ln2_b = (const float*)d_in[26];
  const float* f1W1  = (const float*)d_in[27]; const float* f1b1  = (const float*)d_in[28];
  const float* f1W2  = (const float*)d_in[29]; const float* f1b2  = (const float*)d_in[30];
  const float* Wq_m  = (const float*)d_in[31]; const float* bq_m  = (const float*)d_in[32];
  const float* Wk_m  = (const float*)d_in[33]; const float* bk_m  = (const float*)d_in[34];
  const float* Wv_m  = (const float*)d_in[35]; const float* bv_m  = (const float*)d_in[36];
  const float* Wo_m  = (const float*)d_in[37]; const float* bo_m  = (const float*)d_in[38];
  const float* vln1_g = (const float*)d_in[39]; const float* vln1_b = (const float*)d_in[40];
  const float* vln2_g = (const float*)d_in[41]; const float* vln2_b = (const float*)d_in[42];
  const float* f2W1  = (const float*)d_in[43]; const float* f2b1  = (const float*)d_in[44];
  const float* f2W2  = (const float*)d_in[45]; const float* f2b2  = (const float*)d_in[46];

  const int MV = BB * LV;  // 68000
  float* ws = (float*)d_ws;
  const size_t BIG = (size_t)MV * DD;  // 17,408,000 floats
  float* buf0 = ws;                    // vproj -> moproj -> ff2 accum
  float* buf1 = ws + BIG;              // qh    -> vis1
  float* buf2 = ws + 2 * BIG;          // mo    -> ffn2 hidden chunk
  float* sm   = ws + 3 * BIG;
  float* qb    = sm;              // 65536
  float* offb  = qb + 65536;      // 65536
  float* awlb  = offb + 65536;    // 32768
  float* awb   = awlb + 32768;    // 32768
  float* locb  = awb + 32768;     // 65536
  float* accb  = locb + 65536;    // 65536
  float* doutb = accb + 65536;    // 65536
  float* tattn = doutb + 65536;   // 65536
  float* tres1 = tattn + 65536;   // 65536
  float* ffh   = tres1 + 65536;   // 262144
  float* ffb   = ffh + 262144;    // 65536
  float* khb   = ffb + 65536;     // 65536
  float* vhb   = khb + 65536;     // 65536

  float* out_txt = (float*)d_out;                       // [8,32,256]
  float* out_vis = out_txt + (size_t)BB * LT * DD;      // [8,8500,256]
  float* out_aw  = out_vis + BIG;                       // [8,8500,32]

  dim3 blk(256);
  const dim3 gBig(532, 2);   // ceil(68000/128) x 256/128
  #define NOF nullptr, nullptr, nullptr, nullptr

  // ---- big GEMMs independent of the txt chain ----
  // 1. vproj = value @ W_v + b_v  (value gathered from feats)
  gemm_k<128,128,8,8,AM_FEAT,EP_BIAS><<<gBig, blk, 0, stream>>>(
      nullptr, nullptr, W_v, b_v, buf0, MV, DD, DD, DD, feat0, feat1, feat2, feat3);
  // 2. qh = (vis_tokens + vis_pos) @ Wq_m + bq_m
  gemm_k<128,128,8,8,AM_ADD,EP_BIAS><<<gBig, blk, 0, stream>>>(
      vis_tokens, vis_pos, Wq_m, bq_m, buf1, MV, DD, DD, DD, NOF);

  // ---- txt chain (256 rows) ----
  gemm_k<32,64,2,4,AM_ADD,EP_BIAS><<<dim3(8,4), blk, 0, stream>>>(
      txt_tokens, txt_pos, W_q, b_q, qb, 256, DD, DD, DD, NOF);
  gemm_k<32,64,2,4,AM_PLAIN,EP_BIAS><<<dim3(8,4), blk, 0, stream>>>(
      qb, nullptr, W_off, b_off, offb, 256, DD, DD, DD, NOF);
  gemm_k<32,64,2,4,AM_PLAIN,EP_BIAS><<<dim3(8,2), blk, 0, stream>>>(
      qb, nullptr, W_aw, b_aw, awlb, 256, DD, 128, 128, NOF);
  softloc_kernel<<<8, blk, 0, stream>>>(awlb, offb, refp, awb, locb);
  sampler_kernel<<<256, blk, 0, stream>>>(buf0, locb, awb, accb);
  gemm_k<32,64,2,4,AM_PLAIN,EP_BIAS><<<dim3(8,4), blk, 0, stream>>>(
      accb, nullptr, W_do, b_do, doutb, 256, DD, DD, DD, NOF);
  gemm_k<32,64,2,4,AM_PLAIN,EP_BIAS><<<dim3(8,4), blk, 0, stream>>>(
      doutb, nullptr, W_out, b_out, tattn, 256, DD, DD, DD, NOF);
  ln_kernel<<<64, blk, 0, stream>>>(tattn, txt_tokens, ln1_g, ln1_b, tres1, 256);
  gemm_k<32,64,2,4,AM_PLAIN,EP_GELU><<<dim3(8,16), blk, 0, stream>>>(
      tres1, nullptr, f1W1, f1b1, ffh, 256, DD, 1024, 1024, NOF);
  gemm_k<32,64,2,4,AM_PLAIN,EP_BIAS><<<dim3(8,4), blk, 0, stream>>>(
      ffh, nullptr, f1W2, f1b2, ffb, 256, 1024, DD, DD, NOF);
  ln_kernel<<<64, blk, 0, stream>>>(ffb, tres1, ln2_g, ln2_b, out_txt, 256);

  // kh/vh from vis_key = txt_res + txt_pos
  gemm_k<32,64,2,4,AM_ADD,EP_BIAS><<<dim3(8,4), blk, 0, stream>>>(
      out_txt, txt_pos, Wk_m, bk_m, khb, 256, DD, DD, DD, NOF);
  gemm_k<32,64,2,4,AM_ADD,EP_BIAS><<<dim3(8,4), blk, 0, stream>>>(
      out_txt, txt_pos, Wv_m, bv_m, vhb, 256, DD, DD, DD, NOF);

  // ---- vli attention + output proj + LN ----
  attn_kernel<<<2125, blk, 0, stream>>>(buf1, khb, vhb, buf2, out_aw);
  gemm_k<128,128,8,8,AM_PLAIN,EP_BIAS><<<gBig, blk, 0, stream>>>(
      buf2, nullptr, Wo_m, bo_m, buf0, MV, DD, DD, DD, NOF);
  ln_kernel<<<17000, blk, 0, stream>>>(buf0, vis_tokens, vln1_g, vln1_b, buf1, MV);

  // ---- ffn2: hidden 1024 chunked into 4 x 256 columns ----
  for (int c = 0; c < 4; ++c) {
    gemm_k<128,128,8,8,AM_PLAIN,EP_GELU><<<gBig, blk, 0, stream>>>(
        buf1, nullptr, f2W1 + c * 256, f2b1 + c * 256, buf2, MV, DD, 1024, DD, NOF);
    if (c == 0) {
      gemm_k<128,128,8,8,AM_PLAIN,EP_BIAS><<<gBig, blk, 0, stream>>>(
          buf2, nullptr, f2W2 + (size_t)c * 256 * DD, f2b2, buf0, MV, DD, DD, DD, NOF);
    } else {
      gemm_k<128,128,8,8,AM_PLAIN,EP_ACC><<<gBig, blk, 0, stream>>>(
          buf2, nullptr, f2W2 + (size_t)c * 256 * DD, nullptr, buf0, MV, DD, DD, DD, NOF);
    }
  }
  ln_kernel<<<17000, blk, 0, stream>>>(buf0, buf1, vln2_g, vln2_b, out_vis, MV);
  #undef NOF
}

// Round 2
// 2270.316 us; speedup vs baseline: 1.2346x; 1.2346x over previous
//
#include <hip/hip_runtime.h>
#include <cstddef>

// ---- problem constants ----
#define DD   256
#define NHH  8
#define HDD  32
#define BB   8
#define LT   32
#define LV   8500   // 6400+1600+400+100

__device__ __forceinline__ float gelu_f(float x) {
  // jax.nn.gelu approximate=False: x * 0.5 * (1 + erf(x/sqrt(2)))
  return 0.5f * x * (1.0f + erff(x * 0.70710678118654752440f));
}

enum { AM_PLAIN = 0, AM_ADD = 1, AM_FEAT = 2 };
enum { EP_BIAS = 0, EP_GELU = 1, EP_ACC = 2 };

// Generic fp32 tiled GEMM: C[M x N] = op_epi( A[M x K] @ W[K x N] + bias )
// A-modes: PLAIN (A0), ADD (A0 + A1), FEAT (gather value matrix from [B,D,HW] feats).
// N is implied by gridDim.y * BN (all our Ns are multiples of BN, no col guard).
// lda == K for all callers.
template<int BM, int BN, int TM, int TN, int AMODE, int EPI>
__launch_bounds__(256)
__global__ void gemm_k(const float* __restrict__ A0, const float* __restrict__ A1,
                       const float* __restrict__ Wt, const float* __restrict__ bias,
                       float* __restrict__ C, int M, int K, int ldw, int ldc,
                       const float* __restrict__ f0, const float* __restrict__ f1,
                       const float* __restrict__ f2, const float* __restrict__ f3)
{
  constexpr int BK = 16;
  __shared__ __align__(16) float As[BK][BM];
  __shared__ __align__(16) float Ws[BK][BN];
  const int tid  = threadIdx.x;
  const int row0 = blockIdx.x * BM;
  const int col0 = blockIdx.y * BN;
  const int tx = tid % (BN / TN);
  const int ty = tid / (BN / TN);
  float acc[TM][TN] = {};

  for (int k0 = 0; k0 < K; k0 += BK) {
    if constexpr (AMODE == AM_FEAT) {
      // value[b, s, k] = feat_l[b, k, s - start_l]; load float4 along spatial s.
      constexpr int AU = BM * BK / 4;
      for (int u = tid; u < AU; u += 256) {
        int k  = u / (BM / 4);
        int m4 = (u % (BM / 4)) * 4;
        int grow = row0 + m4;
        float4 v = make_float4(0.f, 0.f, 0.f, 0.f);
        if (grow < M) {
          int b = grow / LV;
          int s = grow - b * LV;
          int l = (s >= 8400) ? 3 : (s >= 8000) ? 2 : (s >= 6400) ? 1 : 0;
          const float* fp = (l == 0) ? f0 : (l == 1) ? f1 : (l == 2) ? f2 : f3;
          const int hw = (l == 0) ? 6400 : (l == 1) ? 1600 : (l == 2) ? 400 : 100;
          const int st = (l == 0) ? 0 : (l == 1) ? 6400 : (l == 2) ? 8000 : 8400;
          v = *(const float4*)(fp + ((size_t)b * DD + (k0 + k)) * hw + (s - st));
        }
        *(float4*)&As[k][m4] = v;
      }
    } else {
      constexpr int AU = BM * BK / 4;
      for (int u = tid; u < AU; u += 256) {
        int m  = u / (BK / 4);
        int kq = (u % (BK / 4)) * 4;
        int grow = row0 + m;
        float4 v = make_float4(0.f, 0.f, 0.f, 0.f);
        if (grow < M) {
          v = *(const float4*)(A0 + (size_t)grow * K + k0 + kq);
          if constexpr (AMODE == AM_ADD) {
            float4 w = *(const float4*)(A1 + (size_t)grow * K + k0 + kq);
            v.x += w.x; v.y += w.y; v.z += w.z; v.w += w.w;
          }
        }
        As[kq + 0][m] = v.x; As[kq + 1][m] = v.y;
        As[kq + 2][m] = v.z; As[kq + 3][m] = v.w;
      }
    }
    {
      constexpr int WU = BK * BN / 4;
      for (int u = tid; u < WU; u += 256) {
        int k  = u / (BN / 4);
        int n4 = (u % (BN / 4)) * 4;
        *(float4*)&Ws[k][n4] =
            *(const float4*)(Wt + (size_t)(k0 + k) * ldw + col0 + n4);
      }
    }
    __syncthreads();

    #pragma unroll
    for (int k = 0; k < BK; ++k) {
      float a[TM], bv[TN];
      if constexpr (TM % 4 == 0) {
        #pragma unroll
        for (int i = 0; i < TM; i += 4) {
          float4 t4 = *(const float4*)&As[k][ty * TM + i];
          a[i] = t4.x; a[i + 1] = t4.y; a[i + 2] = t4.z; a[i + 3] = t4.w;
        }
      } else {
        #pragma unroll
        for (int i = 0; i < TM; ++i) a[i] = As[k][ty * TM + i];
      }
      #pragma unroll
      for (int j = 0; j < TN; j += 4) {
        float4 t4 = *(const float4*)&Ws[k][tx * TN + j];
        bv[j] = t4.x; bv[j + 1] = t4.y; bv[j + 2] = t4.z; bv[j + 3] = t4.w;
      }
      #pragma unroll
      for (int i = 0; i < TM; ++i)
        #pragma unroll
        for (int j = 0; j < TN; ++j)
          acc[i][j] = fmaf(a[i], bv[j], acc[i][j]);
    }
    __syncthreads();
  }

  #pragma unroll
  for (int i = 0; i < TM; ++i) {
    int r = row0 + ty * TM + i;
    if (r >= M) continue;
    #pragma unroll
    for (int j4 = 0; j4 < TN; j4 += 4) {
      int c = col0 + tx * TN + j4;
      float4 v = make_float4(acc[i][j4], acc[i][j4 + 1], acc[i][j4 + 2], acc[i][j4 + 3]);
      if constexpr (EPI == EP_ACC) {
        float4 old = *(const float4*)(C + (size_t)r * ldc + c);
        v.x += old.x; v.y += old.y; v.z += old.z; v.w += old.w;
      } else {
        float4 b4 = *(const float4*)(bias + c);
        v.x += b4.x; v.y += b4.y; v.z += b4.z; v.w += b4.w;
        if constexpr (EPI == EP_GELU) {
          v.x = gelu_f(v.x); v.y = gelu_f(v.y); v.z = gelu_f(v.z); v.w = gelu_f(v.w);
        }
      }
      *(float4*)(C + (size_t)r * ldc + c) = v;
    }
  }
}

// LayerNorm over D=256 with fused residual: O[row] = LN(X[row] + R[row]) * g + b
// One 64-lane wave per row, 4 rows per 256-thread block.
__global__ void ln_kernel(const float* __restrict__ X, const float* __restrict__ R,
                          const float* __restrict__ g, const float* __restrict__ bta,
                          float* __restrict__ O, int M)
{
  int row  = blockIdx.x * 4 + (threadIdx.x >> 6);
  int lane = threadIdx.x & 63;
  if (row >= M) return;
  size_t base = (size_t)row * DD + lane * 4;
  float4 x = *(const float4*)(X + base);
  float4 r = *(const float4*)(R + base);
  x.x += r.x; x.y += r.y; x.z += r.z; x.w += r.w;
  float s  = x.x + x.y + x.z + x.w;
  float s2 = x.x * x.x + x.y * x.y + x.z * x.z + x.w * x.w;
  #pragma unroll
  for (int m = 1; m < 64; m <<= 1) {
    s  += __shfl_xor(s, m);
    s2 += __shfl_xor(s2, m);
  }
  float mean = s * (1.0f / 256.0f);
  float var  = s2 * (1.0f / 256.0f) - mean * mean;
  float rstd = rsqrtf(var + 1e-5f);
  float4 gg = *(const float4*)(g + lane * 4);
  float4 bb = *(const float4*)(bta + lane * 4);
  float4 o;
  o.x = (x.x - mean) * rstd * gg.x + bb.x;
  o.y = (x.y - mean) * rstd * gg.y + bb.y;
  o.z = (x.z - mean) * rstd * gg.z + bb.z;
  o.w = (x.w - mean) * rstd * gg.w + bb.w;
  *(float4*)(O + base) = o;
}

// Per (b,q,h): softmax over NL*NP=16 attention logits; sampling locations
// loc = ref + off / (W_l, H_l). Layouts: awl [row,128] col=h*16+(l*4+p);
// offb/loc [row,256] col = h*32 + l*8 + p*2 + c; refp [row,4,2].
__global__ void softloc_kernel(const float* __restrict__ awl, const float* __restrict__ offb,
                               const float* __restrict__ refp, float* __restrict__ aw,
                               float* __restrict__ loc)
{
  int idx = blockIdx.x * 256 + threadIdx.x;
  if (idx >= BB * LT * NHH) return;
  int h   = idx & 7;
  int row = idx >> 3;
  float v[16]; float mx = -1e30f;
  #pragma unroll
  for (int i = 0; i < 16; ++i) { v[i] = awl[row * 128 + h * 16 + i]; mx = fmaxf(mx, v[i]); }
  float sum = 0.f;
  #pragma unroll
  for (int i = 0; i < 16; ++i) { v[i] = expf(v[i] - mx); sum += v[i]; }
  float inv = 1.0f / sum;
  #pragma unroll
  for (int i = 0; i < 16; ++i) aw[row * 128 + h * 16 + i] = v[i] * inv;
  const float invn[4] = {1.f / 80.f, 1.f / 40.f, 1.f / 20.f, 1.f / 10.f};
  #pragma unroll
  for (int l = 0; l < 4; ++l) {
    float rx = refp[(row * 4 + l) * 2 + 0];
    float ry = refp[(row * 4 + l) * 2 + 1];
    #pragma unroll
    for (int p = 0; p < 4; ++p) {
      int o = row * 256 + h * 32 + l * 8 + p * 2;
      loc[o + 0] = rx + offb[o + 0] * invn[l];
      loc[o + 1] = ry + offb[o + 1] * invn[l];
    }
  }
}

// Deformable sampling: one block per (b,q); thread = (h, hd).
// acc[row, h*32+hd] = sum_{l,p,corners} aw * w_bilinear * vproj[b, start_l+pos, h*32+hd]
__global__ void sampler_kernel(const float* __restrict__ vproj, const float* __restrict__ loc,
                               const float* __restrict__ aw, float* __restrict__ acc)
{
  int row = blockIdx.x;          // b*32 + q
  int t   = threadIdx.x;
  int h   = t >> 5, hd = t & 31;
  int b   = row >> 5;
  const float* vb = vproj + (size_t)b * LV * DD;
  const int Hs[4] = {80, 40, 20, 10};
  const int st[4] = {0, 6400, 8000, 8400};
  float a = 0.f;
  #pragma unroll
  for (int l = 0; l < 4; ++l) {
    const int Wl = Hs[l], Hl = Hs[l];   // square levels
    #pragma unroll
    for (int p = 0; p < 4; ++p) {
      int o = row * 256 + h * 32 + l * 8 + p * 2;
      float lx  = loc[o + 0];
      float ly  = loc[o + 1];
      float wgt = aw[row * 128 + h * 16 + l * 4 + p];
      float x = lx * (float)Wl - 0.5f;
      float y = ly * (float)Hl - 0.5f;
      float x0f = floorf(x), y0f = floorf(y);
      float fx = x - x0f, fy = y - y0f;
      int x0 = (int)x0f, y0 = (int)y0f;
      #pragma unroll
      for (int dy = 0; dy < 2; ++dy) {
        #pragma unroll
        for (int dx = 0; dx < 2; ++dx) {
          int xi = x0 + dx, yi = y0 + dy;
          float w = (dx ? fx : 1.f - fx) * (dy ? fy : 1.f - fy);
          if (xi >= 0 && xi < Wl && yi >= 0 && yi < Hl) {
            a = fmaf(wgt * w, vb[(size_t)(st[l] + yi * Wl + xi) * DD + h * 32 + hd], a);
          }
        }
      }
    }
  }
  acc[(size_t)row * DD + t] = a;
}

// Cross attention (32 keys, HD=32), spill-free layout.
// Block = 512 threads = 16 query rows x 32 lanes. Lane = (head h = l>>2, part = l&3),
// each lane owns 8 of the 32 head-dims. K/V for the block's batch staged in LDS (64 KB).
// Per-thread state: q[8] + o[8] + s[32] = 48 floats (fits VGPRs, no scratch).
__global__ __launch_bounds__(512)
void attn_kernel(const float* __restrict__ qh, const float* __restrict__ kh,
                 const float* __restrict__ vh, float* __restrict__ mo,
                 float* __restrict__ awout)
{
  __shared__ __align__(16) float Ks[32][256];
  __shared__ __align__(16) float Vs[32][256];
  const int b = blockIdx.y;
  {
    const float4* ksrc = (const float4*)(kh + (size_t)b * 32 * DD);
    const float4* vsrc = (const float4*)(vh + (size_t)b * 32 * DD);
    float4* kd = (float4*)&Ks[0][0];
    float4* vd = (float4*)&Vs[0][0];
    for (int u = threadIdx.x; u < 2048; u += 512) { kd[u] = ksrc[u]; vd[u] = vsrc[u]; }
  }
  __syncthreads();

  const int rl   = threadIdx.x >> 5;   // 0..15
  const int l    = threadIdx.x & 31;
  const int h    = l >> 2;
  const int part = l & 3;
  const int s    = blockIdx.x * 16 + rl;
  if (s >= LV) return;                  // tail rows masked (after staging+sync)
  const size_t row = (size_t)b * LV + s;
  const int c0 = h * 32 + part * 8;
  const float scale = 0.17677669529663687f;  // 1/sqrt(32)

  float q[8];
  {
    const float4* qp = (const float4*)(qh + row * DD + c0);
    float4 a = qp[0], c = qp[1];
    q[0]=a.x; q[1]=a.y; q[2]=a.z; q[3]=a.w; q[4]=c.x; q[5]=c.y; q[6]=c.z; q[7]=c.w;
  }

  float sc[32]; float mx = -1e30f;
  #pragma unroll
  for (int k = 0; k < 32; ++k) {
    const float4* kp = (const float4*)&Ks[k][c0];
    float4 a = kp[0], c = kp[1];
    float d = 0.f;
    d = fmaf(q[0], a.x, d); d = fmaf(q[1], a.y, d); d = fmaf(q[2], a.z, d); d = fmaf(q[3], a.w, d);
    d = fmaf(q[4], c.x, d); d = fmaf(q[5], c.y, d); d = fmaf(q[6], c.z, d); d = fmaf(q[7], c.w, d);
    // sum over the 4 quarter-lanes of this head (lane bits 0,1)
    d += __shfl_xor(d, 1);
    d += __shfl_xor(d, 2);
    sc[k] = d * scale;
    mx = fmaxf(mx, sc[k]);
  }
  float sum = 0.f;
  #pragma unroll
  for (int k = 0; k < 32; ++k) { sc[k] = expf(sc[k] - mx); sum += sc[k]; }
  const float inv = 1.0f / sum;
  #pragma unroll
  for (int k = 0; k < 32; ++k) sc[k] *= inv;

  float o[8] = {};
  #pragma unroll
  for (int k = 0; k < 32; ++k) {
    const float4* vp = (const float4*)&Vs[k][c0];
    float4 a = vp[0], c = vp[1];
    const float pk = sc[k];
    o[0] = fmaf(pk, a.x, o[0]); o[1] = fmaf(pk, a.y, o[1]);
    o[2] = fmaf(pk, a.z, o[2]); o[3] = fmaf(pk, a.w, o[3]);
    o[4] = fmaf(pk, c.x, o[4]); o[5] = fmaf(pk, c.y, o[5]);
    o[6] = fmaf(pk, c.z, o[6]); o[7] = fmaf(pk, c.w, o[7]);
  }
  {
    float4* op = (float4*)(mo + row * DD + c0);
    op[0] = make_float4(o[0], o[1], o[2], o[3]);
    op[1] = make_float4(o[4], o[5], o[6], o[7]);
  }
  // head-mean of p: reduce over head bits (lane bits 2,3,4); lanes h==0 write.
  #pragma unroll
  for (int k = 0; k < 32; ++k) {
    float v = sc[k];
    v += __shfl_xor(v, 4);
    v += __shfl_xor(v, 8);
    v += __shfl_xor(v, 16);
    if (h == 0 && (k >> 3) == part) awout[row * 32 + k] = v * 0.125f;
  }
}

extern "C" void kernel_launch(void* const* d_in, const int* in_sizes, int n_in,
                              void* d_out, int out_size, void* d_ws, size_t ws_size,
                              hipStream_t stream)
{
  const float* txt_tokens = (const float*)d_in[0];
  const float* vis_tokens = (const float*)d_in[1];
  const float* feat0 = (const float*)d_in[2];
  const float* feat1 = (const float*)d_in[3];
  const float* feat2 = (const float*)d_in[4];
  const float* feat3 = (const float*)d_in[5];
  // d_in[6] spatial_shapes, d_in[7] level_start_index — compile-time constants here
  const float* refp    = (const float*)d_in[8];
  const float* txt_pos = (const float*)d_in[9];
  const float* vis_pos = (const float*)d_in[10];
  const float* W_off = (const float*)d_in[11]; const float* b_off = (const float*)d_in[12];
  const float* W_aw  = (const float*)d_in[13]; const float* b_aw  = (const float*)d_in[14];
  const float* W_v   = (const float*)d_in[15]; const float* b_v   = (const float*)d_in[16];
  const float* W_do  = (const float*)d_in[17]; const float* b_do  = (const float*)d_in[18];
  const float* W_q   = (const float*)d_in[19]; const float* b_q   = (const float*)d_in[20];
  const float* W_out = (const float*)d_in[21]; const float* b_out = (const float*)d_in[22];
  const float* ln1_g = (const float*)d_in[23]; const float* ln1_b = (const float*)d_in[24];
  const float* ln2_g = (const float*)d_in[25]; const float* ln2_b = (const float*)d_in[26];
  const float* f1W1  = (const float*)d_in[27]; const float* f1b1  = (const float*)d_in[28];
  const float* f1W2  = (const float*)d_in[29]; const float* f1b2  = (const float*)d_in[30];
  const float* Wq_m  = (const float*)d_in[31]; const float* bq_m  = (const float*)d_in[32];
  const float* Wk_m  = (const float*)d_in[33]; const float* bk_m  = (const float*)d_in[34];
  const float* Wv_m  = (const float*)d_in[35]; const float* bv_m  = (const float*)d_in[36];
  const float* Wo_m  = (const float*)d_in[37]; const float* bo_m  = (const float*)d_in[38];
  const float* vln1_g = (const float*)d_in[39]; const float* vln1_b = (const float*)d_in[40];
  const float* vln2_g = (const float*)d_in[41]; const float* vln2_b = (const float*)d_in[42];
  const float* f2W1  = (const float*)d_in[43]; const float* f2b1  = (const float*)d_in[44];
  const float* f2W2  = (const float*)d_in[45]; const float* f2b2  = (const float*)d_in[46];

  const int MV = BB * LV;  // 68000
  float* ws = (float*)d_ws;
  const size_t BIG = (size_t)MV * DD;  // 17,408,000 floats
  float* buf0 = ws;                    // vproj -> moproj -> ff2 accum
  float* buf1 = ws + BIG;              // qh    -> vis1
  float* buf2 = ws + 2 * BIG;          // mo    -> ffn2 hidden chunk
  float* sm   = ws + 3 * BIG;
  float* qb    = sm;              // 65536
  float* offb  = qb + 65536;      // 65536
  float* awlb  = offb + 65536;    // 32768
  float* awb   = awlb + 32768;    // 32768
  float* locb  = awb + 32768;     // 65536
  float* accb  = locb + 65536;    // 65536
  float* doutb = accb + 65536;    // 65536
  float* tattn = doutb + 65536;   // 65536
  float* tres1 = tattn + 65536;   // 65536
  float* ffh   = tres1 + 65536;   // 262144
  float* ffb   = ffh + 262144;    // 65536
  float* khb   = ffb + 65536;     // 65536
  float* vhb   = khb + 65536;     // 65536

  float* out_txt = (float*)d_out;                       // [8,32,256]
  float* out_vis = out_txt + (size_t)BB * LT * DD;      // [8,8500,256]
  float* out_aw  = out_vis + BIG;                       // [8,8500,32]

  dim3 blk(256);
  const dim3 gBig(532, 2);   // ceil(68000/128) x 256/128
  #define NOF nullptr, nullptr, nullptr, nullptr

  // ---- big GEMMs independent of the txt chain ----
  // 1. vproj = value @ W_v + b_v  (value gathered from feats)
  gemm_k<128,128,8,8,AM_FEAT,EP_BIAS><<<gBig, blk, 0, stream>>>(
      nullptr, nullptr, W_v, b_v, buf0, MV, DD, DD, DD, feat0, feat1, feat2, feat3);
  // 2. qh = (vis_tokens + vis_pos) @ Wq_m + bq_m
  gemm_k<128,128,8,8,AM_ADD,EP_BIAS><<<gBig, blk, 0, stream>>>(
      vis_tokens, vis_pos, Wq_m, bq_m, buf1, MV, DD, DD, DD, NOF);

  // ---- txt chain (256 rows) ----
  gemm_k<32,64,2,4,AM_ADD,EP_BIAS><<<dim3(8,4), blk, 0, stream>>>(
      txt_tokens, txt_pos, W_q, b_q, qb, 256, DD, DD, DD, NOF);
  gemm_k<32,64,2,4,AM_PLAIN,EP_BIAS><<<dim3(8,4), blk, 0, stream>>>(
      qb, nullptr, W_off, b_off, offb, 256, DD, DD, DD, NOF);
  gemm_k<32,64,2,4,AM_PLAIN,EP_BIAS><<<dim3(8,2), blk, 0, stream>>>(
      qb, nullptr, W_aw, b_aw, awlb, 256, DD, 128, 128, NOF);
  softloc_kernel<<<8, blk, 0, stream>>>(awlb, offb, refp, awb, locb);
  sampler_kernel<<<256, blk, 0, stream>>>(buf0, locb, awb, accb);
  gemm_k<32,64,2,4,AM_PLAIN,EP_BIAS><<<dim3(8,4), blk, 0, stream>>>(
      accb, nullptr, W_do, b_do, doutb, 256, DD, DD, DD, NOF);
  gemm_k<32,64,2,4,AM_PLAIN,EP_BIAS><<<dim3(8,4), blk, 0, stream>>>(
      doutb, nullptr, W_out, b_out, tattn, 256, DD, DD, DD, NOF);
  ln_kernel<<<64, blk, 0, stream>>>(tattn, txt_tokens, ln1_g, ln1_b, tres1, 256);
  gemm_k<32,64,2,4,AM_PLAIN,EP_GELU><<<dim3(8,16), blk, 0, stream>>>(
      tres1, nullptr, f1W1, f1b1, ffh, 256, DD, 1024, 1024, NOF);
  gemm_k<32,64,2,4,AM_PLAIN,EP_BIAS><<<dim3(8,4), blk, 0, stream>>>(
      ffh, nullptr, f1W2, f1b2, ffb, 256, 1024, DD, DD, NOF);
  ln_kernel<<<64, blk, 0, stream>>>(ffb, tres1, ln2_g, ln2_b, out_txt, 256);

  // kh/vh from vis_key = txt_res + txt_pos
  gemm_k<32,64,2,4,AM_ADD,EP_BIAS><<<dim3(8,4), blk, 0, stream>>>(
      out_txt, txt_pos, Wk_m, bk_m, khb, 256, DD, DD, DD, NOF);
  gemm_k<32,64,2,4,AM_ADD,EP_BIAS><<<dim3(8,4), blk, 0, stream>>>(
      out_txt, txt_pos, Wv_m, bv_m, vhb, 256, DD, DD, DD, NOF);

  // ---- vli attention + output proj + LN ----
  attn_kernel<<<dim3(532, 8), dim3(512), 0, stream>>>(buf1, khb, vhb, buf2, out_aw);
  gemm_k<128,128,8,8,AM_PLAIN,EP_BIAS><<<gBig, blk, 0, stream>>>(
      buf2, nullptr, Wo_m, bo_m, buf0, MV, DD, DD, DD, NOF);
  ln_kernel<<<17000, blk, 0, stream>>>(buf0, vis_tokens, vln1_g, vln1_b, buf1, MV);

  // ---- ffn2: hidden 1024 chunked into 4 x 256 columns ----
  for (int c = 0; c < 4; ++c) {
    gemm_k<128,128,8,8,AM_PLAIN,EP_GELU><<<gBig, blk, 0, stream>>>(
        buf1, nullptr, f2W1 + c * 256, f2b1 + c * 256, buf2, MV, DD, 1024, DD, NOF);
    if (c == 0) {
      gemm_k<128,128,8,8,AM_PLAIN,EP_BIAS><<<gBig, blk, 0, stream>>>(
          buf2, nullptr, f2W2 + (size_t)c * 256 * DD, f2b2, buf0, MV, DD, DD, DD, NOF);
    } else {
      gemm_k<128,128,8,8,AM_PLAIN,EP_ACC><<<gBig, blk, 0, stream>>>(
          buf2, nullptr, f2W2 + (size_t)c * 256 * DD, nullptr, buf0, MV, DD, DD, DD, NOF);
    }
  }
  ln_kernel<<<17000, blk, 0, stream>>>(buf0, buf1, vln2_g, vln2_b, out_vis, MV);
  #undef NOF
}

// Round 3
// 1301.702 us; speedup vs baseline: 2.1533x; 1.7441x over previous
//
#include <hip/hip_runtime.h>
#include <cstddef>

// ---- problem constants ----
#define DD   256
#define NHH  8
#define HDD  32
#define BB   8
#define LT   32
#define LV   8500   // 6400+1600+400+100

typedef unsigned short u16;
typedef unsigned int   u32;
typedef __attribute__((ext_vector_type(8))) short short8;
typedef __attribute__((ext_vector_type(8))) unsigned short ushort8;
typedef __attribute__((ext_vector_type(4))) float f32x4;

__device__ __forceinline__ float gelu_f(float x) {
  // jax.nn.gelu approximate=False: x * 0.5 * (1 + erf(x/sqrt(2)))
  return 0.5f * x * (1.0f + erff(x * 0.70710678118654752440f));
}

// fp32 -> bf16 round-to-nearest-even
__device__ __forceinline__ u16 f2bf(float x) {
  u32 u = __float_as_uint(x);
  u += 0x7FFFu + ((u >> 16) & 1u);
  return (u16)(u >> 16);
}
__device__ __forceinline__ float bf2f(u16 h) { return __uint_as_float((u32)h << 16); }

enum { AM_PLAIN = 0, AM_ADD = 1, AM_FEAT = 2 };
enum { EP_BIAS = 0, EP_GELU = 1, EP_ACC = 2 };

// ======================= fp32 tiled GEMM (small txt-side only) =======================
template<int BM, int BN, int TM, int TN, int AMODE, int EPI>
__launch_bounds__(256)
__global__ void gemm_k(const float* __restrict__ A0, const float* __restrict__ A1,
                       const float* __restrict__ Wt, const float* __restrict__ bias,
                       float* __restrict__ C, int M, int K, int ldw, int ldc)
{
  constexpr int BK = 16;
  __shared__ __align__(16) float As[BK][BM];
  __shared__ __align__(16) float Ws[BK][BN];
  const int tid  = threadIdx.x;
  const int row0 = blockIdx.x * BM;
  const int col0 = blockIdx.y * BN;
  const int tx = tid % (BN / TN);
  const int ty = tid / (BN / TN);
  float acc[TM][TN] = {};

  for (int k0 = 0; k0 < K; k0 += BK) {
    {
      constexpr int AU = BM * BK / 4;
      for (int u = tid; u < AU; u += 256) {
        int m  = u / (BK / 4);
        int kq = (u % (BK / 4)) * 4;
        int grow = row0 + m;
        float4 v = make_float4(0.f, 0.f, 0.f, 0.f);
        if (grow < M) {
          v = *(const float4*)(A0 + (size_t)grow * K + k0 + kq);
          if constexpr (AMODE == AM_ADD) {
            float4 w = *(const float4*)(A1 + (size_t)grow * K + k0 + kq);
            v.x += w.x; v.y += w.y; v.z += w.z; v.w += w.w;
          }
        }
        As[kq + 0][m] = v.x; As[kq + 1][m] = v.y;
        As[kq + 2][m] = v.z; As[kq + 3][m] = v.w;
      }
    }
    {
      constexpr int WU = BK * BN / 4;
      for (int u = tid; u < WU; u += 256) {
        int k  = u / (BN / 4);
        int n4 = (u % (BN / 4)) * 4;
        *(float4*)&Ws[k][n4] =
            *(const float4*)(Wt + (size_t)(k0 + k) * ldw + col0 + n4);
      }
    }
    __syncthreads();

    #pragma unroll
    for (int k = 0; k < BK; ++k) {
      float a[TM], bv[TN];
      #pragma unroll
      for (int i = 0; i < TM; ++i) a[i] = As[k][ty * TM + i];
      #pragma unroll
      for (int j = 0; j < TN; j += 4) {
        float4 t4 = *(const float4*)&Ws[k][tx * TN + j];
        bv[j] = t4.x; bv[j + 1] = t4.y; bv[j + 2] = t4.z; bv[j + 3] = t4.w;
      }
      #pragma unroll
      for (int i = 0; i < TM; ++i)
        #pragma unroll
        for (int j = 0; j < TN; ++j)
          acc[i][j] = fmaf(a[i], bv[j], acc[i][j]);
    }
    __syncthreads();
  }

  #pragma unroll
  for (int i = 0; i < TM; ++i) {
    int r = row0 + ty * TM + i;
    if (r >= M) continue;
    #pragma unroll
    for (int j4 = 0; j4 < TN; j4 += 4) {
      int c = col0 + tx * TN + j4;
      float4 v = make_float4(acc[i][j4], acc[i][j4 + 1], acc[i][j4 + 2], acc[i][j4 + 3]);
      float4 b4 = *(const float4*)(bias + c);
      v.x += b4.x; v.y += b4.y; v.z += b4.z; v.w += b4.w;
      if constexpr (EPI == EP_GELU) {
        v.x = gelu_f(v.x); v.y = gelu_f(v.y); v.z = gelu_f(v.z); v.w = gelu_f(v.w);
      }
      *(float4*)(C + (size_t)r * ldc + c) = v;
    }
  }
}

// ======================= weight split prep =======================
// out[((k>>3)*Nw + n)*8 + (k&7)] = hi/lo bf16 of W[k][n]  (fragment-ready layout)
__global__ void wsplit_kernel(const float* __restrict__ W, u16* __restrict__ hi,
                              u16* __restrict__ lo, int total, int Nw)
{
  int id = blockIdx.x * 256 + threadIdx.x;
  if (id >= total) return;
  int k = id / Nw, n = id - k * Nw;
  float x = W[id];
  u16 h = f2bf(x);
  u16 l = f2bf(x - bf2f(h));
  int o = ((k >> 3) * Nw + n) * 8 + (k & 7);
  hi[o] = h; lo[o] = l;
}

// ======================= split-bf16 MFMA GEMM =======================
// C[M x N] = epi( A[M x K] @ W[K x Nw (window wcol0..)] + bias )
// AMODE: 0 plain fp32, 1 add two fp32, 2 feat-gather fp32, 3 bf16 (hi-only A)
// EPI:   0 +bias -> fp32, 1 +bias,gelu -> bf16, 2 accumulate into fp32 C (no bias)
// 3-term split product (2-term when AMODE==3). Tile 128x128xBK32, 4 waves x (64x64).
template<int AMODE, int EPI>
__global__ __launch_bounds__(256) void mgemm(
    const void* __restrict__ Ap, const float* __restrict__ A1,
    const u16* __restrict__ Whi, const u16* __restrict__ Wlo,
    const float* __restrict__ bias, void* __restrict__ Cp,
    int M, int K, int lda, int ldc, int Nw, int wcol0, int ks0,
    const float* __restrict__ f0, const float* __restrict__ f1,
    const float* __restrict__ f2, const float* __restrict__ f3)
{
  // slot-major LDS: [slot(4)][row(128)+pad][8 bf16] ; slot = k/8 within BK=32
  __shared__ __align__(16) u16 Ahi[4 * 129 * 8];
  __shared__ __align__(16) u16 Alo[4 * 129 * 8];
  const int tid  = threadIdx.x;
  const int lane = tid & 63;
  const int w    = tid >> 6;
  const int wr   = w >> 1, wc = w & 1;
  const int row0  = blockIdx.x * 128;
  const int colC0 = blockIdx.y * 128;
  f32x4 acc[4][4] = {};

  const int nk = K >> 5;
  for (int kt = 0; kt < nk; ++kt) {
    if constexpr (AMODE == 3) {
      const u16* Ab = (const u16*)Ap;
      #pragma unroll
      for (int p = 0; p < 2; ++p) {
        int j = tid + p * 256;           // 512 units: (row, slot)
        int row = j >> 2, slot = j & 3;
        int gr = row0 + row;
        ushort8 v = {};
        if (gr < M) v = *(const ushort8*)(Ab + (size_t)gr * lda + kt * 32 + slot * 8);
        *(ushort8*)&Ahi[(slot * 129 + row) * 8] = v;
      }
    } else {
      #pragma unroll
      for (int p = 0; p < 4; ++p) {
        int j = tid + p * 256;           // 1024 float4 units
        int row, f4;
        if constexpr (AMODE == 2) { f4 = j >> 7; row = j & 127; }
        else                      { row = j >> 3; f4 = j & 7; }
        int gr = row0 + row;
        float4 v = make_float4(0.f, 0.f, 0.f, 0.f);
        if (gr < M) {
          if constexpr (AMODE == 2) {
            int b = gr / LV;
            int s = gr - b * LV;
            int l = (s >= 8400) ? 3 : (s >= 8000) ? 2 : (s >= 6400) ? 1 : 0;
            const float* fp = (l == 0) ? f0 : (l == 1) ? f1 : (l == 2) ? f2 : f3;
            const int hw = (l == 0) ? 6400 : (l == 1) ? 1600 : (l == 2) ? 400 : 100;
            const int st = (l == 0) ? 0 : (l == 1) ? 6400 : (l == 2) ? 8000 : 8400;
            const float* base = fp + ((size_t)b * DD + (kt * 32 + f4 * 4)) * hw + (s - st);
            v.x = base[0];
            v.y = base[(size_t)hw];
            v.z = base[2 * (size_t)hw];
            v.w = base[3 * (size_t)hw];
          } else {
            const float* Af = (const float*)Ap;
            v = *(const float4*)(Af + (size_t)gr * lda + kt * 32 + f4 * 4);
            if constexpr (AMODE == 1) {
              float4 u2 = *(const float4*)(A1 + (size_t)gr * lda + kt * 32 + f4 * 4);
              v.x += u2.x; v.y += u2.y; v.z += u2.z; v.w += u2.w;
            }
          }
        }
        int slot = f4 >> 1, half = f4 & 1;
        int off = (slot * 129 + row) * 8 + half * 4;
        u16 h0 = f2bf(v.x), h1 = f2bf(v.y), h2 = f2bf(v.z), h3 = f2bf(v.w);
        uint2 hp; hp.x = (u32)h0 | ((u32)h1 << 16); hp.y = (u32)h2 | ((u32)h3 << 16);
        *(uint2*)&Ahi[off] = hp;
        u16 l0 = f2bf(v.x - bf2f(h0)), l1 = f2bf(v.y - bf2f(h1));
        u16 l2 = f2bf(v.z - bf2f(h2)), l3 = f2bf(v.w - bf2f(h3));
        uint2 lp; lp.x = (u32)l0 | ((u32)l1 << 16); lp.y = (u32)l2 | ((u32)l3 << 16);
        *(uint2*)&Alo[off] = lp;
      }
    }
    __syncthreads();

    const int slot = lane >> 4;
    const int lrow = lane & 15;
    short8 ah[4], al[4], bh[4], bl[4];
    #pragma unroll
    for (int m = 0; m < 4; ++m) {
      int off = (slot * 129 + wr * 64 + m * 16 + lrow) * 8;
      ah[m] = *(const short8*)&Ahi[off];
      if constexpr (AMODE != 3) al[m] = *(const short8*)&Alo[off];
    }
    #pragma unroll
    for (int n = 0; n < 4; ++n) {
      size_t off = ((size_t)((ks0 + kt) * 4 + slot) * Nw + wcol0 + colC0 + wc * 64 + n * 16 + lrow) * 8;
      bh[n] = *(const short8*)(Whi + off);
      bl[n] = *(const short8*)(Wlo + off);
    }
    #pragma unroll
    for (int m = 0; m < 4; ++m)
      #pragma unroll
      for (int n = 0; n < 4; ++n) {
        acc[m][n] = __builtin_amdgcn_mfma_f32_16x16x32_bf16(ah[m], bh[n], acc[m][n], 0, 0, 0);
        acc[m][n] = __builtin_amdgcn_mfma_f32_16x16x32_bf16(ah[m], bl[n], acc[m][n], 0, 0, 0);
        if constexpr (AMODE != 3)
          acc[m][n] = __builtin_amdgcn_mfma_f32_16x16x32_bf16(al[m], bh[n], acc[m][n], 0, 0, 0);
      }
    __syncthreads();
  }

  // epilogue: C/D frag mapping col=lane&15, row=(lane>>4)*4+j  [m89-verified]
  const int lrow = lane & 15;
  #pragma unroll
  for (int m = 0; m < 4; ++m) {
    #pragma unroll
    for (int j = 0; j < 4; ++j) {
      int r = row0 + wr * 64 + m * 16 + ((lane >> 4) << 2) + j;
      if (r >= M) continue;
      #pragma unroll
      for (int n = 0; n < 4; ++n) {
        int c = colC0 + wc * 64 + n * 16 + lrow;
        float v = acc[m][n][j];
        if constexpr (EPI == 0) {
          ((float*)Cp)[(size_t)r * ldc + c] = v + bias[c];
        } else if constexpr (EPI == 1) {
          ((u16*)Cp)[(size_t)r * ldc + c] = f2bf(gelu_f(v + bias[c]));
        } else {
          ((float*)Cp)[(size_t)r * ldc + c] += v;
        }
      }
    }
  }
}

// ======================= LayerNorm (fused residual) =======================
__global__ void ln_kernel(const float* __restrict__ X, const float* __restrict__ R,
                          const float* __restrict__ g, const float* __restrict__ bta,
                          float* __restrict__ O, int M)
{
  int row  = blockIdx.x * 4 + (threadIdx.x >> 6);
  int lane = threadIdx.x & 63;
  if (row >= M) return;
  size_t base = (size_t)row * DD + lane * 4;
  float4 x = *(const float4*)(X + base);
  float4 r = *(const float4*)(R + base);
  x.x += r.x; x.y += r.y; x.z += r.z; x.w += r.w;
  float s  = x.x + x.y + x.z + x.w;
  float s2 = x.x * x.x + x.y * x.y + x.z * x.z + x.w * x.w;
  #pragma unroll
  for (int m = 1; m < 64; m <<= 1) {
    s  += __shfl_xor(s, m);
    s2 += __shfl_xor(s2, m);
  }
  float mean = s * (1.0f / 256.0f);
  float var  = s2 * (1.0f / 256.0f) - mean * mean;
  float rstd = rsqrtf(var + 1e-5f);
  float4 gg = *(const float4*)(g + lane * 4);
  float4 bb = *(const float4*)(bta + lane * 4);
  float4 o;
  o.x = (x.x - mean) * rstd * gg.x + bb.x;
  o.y = (x.y - mean) * rstd * gg.y + bb.y;
  o.z = (x.z - mean) * rstd * gg.z + bb.z;
  o.w = (x.w - mean) * rstd * gg.w + bb.w;
  *(float4*)(O + base) = o;
}

// ======================= deformable softmax+loc =======================
__global__ void softloc_kernel(const float* __restrict__ awl, const float* __restrict__ offb,
                               const float* __restrict__ refp, float* __restrict__ aw,
                               float* __restrict__ loc)
{
  int idx = blockIdx.x * 256 + threadIdx.x;
  if (idx >= BB * LT * NHH) return;
  int h   = idx & 7;
  int row = idx >> 3;
  float v[16]; float mx = -1e30f;
  #pragma unroll
  for (int i = 0; i < 16; ++i) { v[i] = awl[row * 128 + h * 16 + i]; mx = fmaxf(mx, v[i]); }
  float sum = 0.f;
  #pragma unroll
  for (int i = 0; i < 16; ++i) { v[i] = expf(v[i] - mx); sum += v[i]; }
  float inv = 1.0f / sum;
  #pragma unroll
  for (int i = 0; i < 16; ++i) aw[row * 128 + h * 16 + i] = v[i] * inv;
  const float invn[4] = {1.f / 80.f, 1.f / 40.f, 1.f / 20.f, 1.f / 10.f};
  #pragma unroll
  for (int l = 0; l < 4; ++l) {
    float rx = refp[(row * 4 + l) * 2 + 0];
    float ry = refp[(row * 4 + l) * 2 + 1];
    #pragma unroll
    for (int p = 0; p < 4; ++p) {
      int o = row * 256 + h * 32 + l * 8 + p * 2;
      loc[o + 0] = rx + offb[o + 0] * invn[l];
      loc[o + 1] = ry + offb[o + 1] * invn[l];
    }
  }
}

// ======================= deformable sampler =======================
__global__ void sampler_kernel(const float* __restrict__ vproj, const float* __restrict__ loc,
                               const float* __restrict__ aw, float* __restrict__ acc)
{
  int row = blockIdx.x;          // b*32 + q
  int t   = threadIdx.x;
  int h   = t >> 5, hd = t & 31;
  int b   = row >> 5;
  const float* vb = vproj + (size_t)b * LV * DD;
  const int Hs[4] = {80, 40, 20, 10};
  const int st[4] = {0, 6400, 8000, 8400};
  float a = 0.f;
  #pragma unroll
  for (int l = 0; l < 4; ++l) {
    const int Wl = Hs[l], Hl = Hs[l];
    #pragma unroll
    for (int p = 0; p < 4; ++p) {
      int o = row * 256 + h * 32 + l * 8 + p * 2;
      float lx  = loc[o + 0];
      float ly  = loc[o + 1];
      float wgt = aw[row * 128 + h * 16 + l * 4 + p];
      float x = lx * (float)Wl - 0.5f;
      float y = ly * (float)Hl - 0.5f;
      float x0f = floorf(x), y0f = floorf(y);
      float fx = x - x0f, fy = y - y0f;
      int x0 = (int)x0f, y0 = (int)y0f;
      #pragma unroll
      for (int dy = 0; dy < 2; ++dy) {
        #pragma unroll
        for (int dx = 0; dx < 2; ++dx) {
          int xi = x0 + dx, yi = y0 + dy;
          float w2 = (dx ? fx : 1.f - fx) * (dy ? fy : 1.f - fy);
          if (xi >= 0 && xi < Wl && yi >= 0 && yi < Hl) {
            a = fmaf(wgt * w2, vb[(size_t)(st[l] + yi * Wl + xi) * DD + h * 32 + hd], a);
          }
        }
      }
    }
  }
  acc[(size_t)row * DD + t] = a;
}

// ======================= cross attention (32 keys) =======================
__global__ __launch_bounds__(512)
void attn_kernel(const float* __restrict__ qh, const float* __restrict__ kh,
                 const float* __restrict__ vh, float* __restrict__ mo,
                 float* __restrict__ awout)
{
  __shared__ __align__(16) float Ks[32][256];
  __shared__ __align__(16) float Vs[32][256];
  const int b = blockIdx.y;
  {
    const float4* ksrc = (const float4*)(kh + (size_t)b * 32 * DD);
    const float4* vsrc = (const float4*)(vh + (size_t)b * 32 * DD);
    float4* kd = (float4*)&Ks[0][0];
    float4* vd = (float4*)&Vs[0][0];
    for (int u = threadIdx.x; u < 2048; u += 512) { kd[u] = ksrc[u]; vd[u] = vsrc[u]; }
  }
  __syncthreads();

  const int rl   = threadIdx.x >> 5;
  const int l    = threadIdx.x & 31;
  const int h    = l >> 2;
  const int part = l & 3;
  const int s    = blockIdx.x * 16 + rl;
  if (s >= LV) return;
  const size_t row = (size_t)b * LV + s;
  const int c0 = h * 32 + part * 8;
  const float scale = 0.17677669529663687f;

  float q[8];
  {
    const float4* qp = (const float4*)(qh + row * DD + c0);
    float4 a = qp[0], c = qp[1];
    q[0]=a.x; q[1]=a.y; q[2]=a.z; q[3]=a.w; q[4]=c.x; q[5]=c.y; q[6]=c.z; q[7]=c.w;
  }

  float sc[32]; float mx = -1e30f;
  #pragma unroll
  for (int k = 0; k < 32; ++k) {
    const float4* kp = (const float4*)&Ks[k][c0];
    float4 a = kp[0], c = kp[1];
    float d = 0.f;
    d = fmaf(q[0], a.x, d); d = fmaf(q[1], a.y, d); d = fmaf(q[2], a.z, d); d = fmaf(q[3], a.w, d);
    d = fmaf(q[4], c.x, d); d = fmaf(q[5], c.y, d); d = fmaf(q[6], c.z, d); d = fmaf(q[7], c.w, d);
    d += __shfl_xor(d, 1);
    d += __shfl_xor(d, 2);
    sc[k] = d * scale;
    mx = fmaxf(mx, sc[k]);
  }
  float sum = 0.f;
  #pragma unroll
  for (int k = 0; k < 32; ++k) { sc[k] = expf(sc[k] - mx); sum += sc[k]; }
  const float inv = 1.0f / sum;
  #pragma unroll
  for (int k = 0; k < 32; ++k) sc[k] *= inv;

  float o[8] = {};
  #pragma unroll
  for (int k = 0; k < 32; ++k) {
    const float4* vp = (const float4*)&Vs[k][c0];
    float4 a = vp[0], c = vp[1];
    const float pk = sc[k];
    o[0] = fmaf(pk, a.x, o[0]); o[1] = fmaf(pk, a.y, o[1]);
    o[2] = fmaf(pk, a.z, o[2]); o[3] = fmaf(pk, a.w, o[3]);
    o[4] = fmaf(pk, c.x, o[4]); o[5] = fmaf(pk, c.y, o[5]);
    o[6] = fmaf(pk, c.z, o[6]); o[7] = fmaf(pk, c.w, o[7]);
  }
  {
    float4* op = (float4*)(mo + row * DD + c0);
    op[0] = make_float4(o[0], o[1], o[2], o[3]);
    op[1] = make_float4(o[4], o[5], o[6], o[7]);
  }
  #pragma unroll
  for (int k = 0; k < 32; ++k) {
    float v = sc[k];
    v += __shfl_xor(v, 4);
    v += __shfl_xor(v, 8);
    v += __shfl_xor(v, 16);
    if (h == 0 && (k >> 3) == part) awout[row * 32 + k] = v * 0.125f;
  }
}

extern "C" void kernel_launch(void* const* d_in, const int* in_sizes, int n_in,
                              void* d_out, int out_size, void* d_ws, size_t ws_size,
                              hipStream_t stream)
{
  const float* txt_tokens = (const float*)d_in[0];
  const float* vis_tokens = (const float*)d_in[1];
  const float* feat0 = (const float*)d_in[2];
  const float* feat1 = (const float*)d_in[3];
  const float* feat2 = (const float*)d_in[4];
  const float* feat3 = (const float*)d_in[5];
  const float* refp    = (const float*)d_in[8];
  const float* txt_pos = (const float*)d_in[9];
  const float* vis_pos = (const float*)d_in[10];
  const float* W_off = (const float*)d_in[11]; const float* b_off = (const float*)d_in[12];
  const float* W_aw  = (const float*)d_in[13]; const float* b_aw  = (const float*)d_in[14];
  const float* W_v   = (const float*)d_in[15]; const float* b_v   = (const float*)d_in[16];
  const float* W_do  = (const float*)d_in[17]; const float* b_do  = (const float*)d_in[18];
  const float* W_q   = (const float*)d_in[19]; const float* b_q   = (const float*)d_in[20];
  const float* W_out = (const float*)d_in[21]; const float* b_out = (const float*)d_in[22];
  const float* ln1_g = (const float*)d_in[23]; const float* ln1_b = (const float*)d_in[24];
  const float* ln2_g = (const float*)d_in[25]; const float* ln2_b = (const float*)d_in[26];
  const float* f1W1  = (const float*)d_in[27]; const float* f1b1  = (const float*)d_in[28];
  const float* f1W2  = (const float*)d_in[29]; const float* f1b2  = (const float*)d_in[30];
  const float* Wq_m  = (const float*)d_in[31]; const float* bq_m  = (const float*)d_in[32];
  const float* Wk_m  = (const float*)d_in[33]; const float* bk_m  = (const float*)d_in[34];
  const float* Wv_m  = (const float*)d_in[35]; const float* bv_m  = (const float*)d_in[36];
  const float* Wo_m  = (const float*)d_in[37]; const float* bo_m  = (const float*)d_in[38];
  const float* vln1_g = (const float*)d_in[39]; const float* vln1_b = (const float*)d_in[40];
  const float* vln2_g = (const float*)d_in[41]; const float* vln2_b = (const float*)d_in[42];
  const float* f2W1  = (const float*)d_in[43]; const float* f2b1  = (const float*)d_in[44];
  const float* f2W2  = (const float*)d_in[45]; const float* f2b2  = (const float*)d_in[46];

  const int MV = BB * LV;  // 68000
  float* ws = (float*)d_ws;
  const size_t BIG = (size_t)MV * DD;  // 17,408,000 floats
  float* buf0 = ws;                    // vproj -> moproj -> ff2 accum
  float* buf1 = ws + BIG;              // qh    -> vis1
  float* buf2 = ws + 2 * BIG;          // mo    -> ffn2 hidden (bf16)
  float* sm   = ws + 3 * BIG;
  float* qb    = sm;              // 65536
  float* offb  = qb + 65536;
  float* awlb  = offb + 65536;    // 32768
  float* awb   = awlb + 32768;    // 32768
  float* locb  = awb + 32768;     // 65536
  float* accb  = locb + 65536;    // 65536
  float* doutb = accb + 65536;    // 65536
  float* tattn = doutb + 65536;   // 65536
  float* tres1 = tattn + 65536;   // 65536
  float* ffh   = tres1 + 65536;   // 262144
  float* ffb   = ffh + 262144;    // 65536
  float* khb   = ffb + 65536;     // 65536
  float* vhb   = khb + 65536;     // 65536
  // split-weight buffers (u16), 16B-aligned region
  u16* wsp   = (u16*)(vhb + 65536);
  u16* wv_hi = wsp;               u16* wv_lo = wv_hi + 65536;
  u16* wq_hi = wv_lo + 65536;     u16* wq_lo = wq_hi + 65536;
  u16* wo_hi = wq_lo + 65536;     u16* wo_lo = wo_hi + 65536;
  u16* w1_hi = wo_lo + 65536;     u16* w1_lo = w1_hi + 262144;
  u16* w2_hi = w1_lo + 262144;    u16* w2_lo = w2_hi + 262144;

  float* out_txt = (float*)d_out;                       // [8,32,256]
  float* out_vis = out_txt + (size_t)BB * LT * DD;      // [8,8500,256]
  float* out_aw  = out_vis + BIG;                       // [8,8500,32]

  dim3 blk(256);
  #define NOF nullptr, nullptr, nullptr, nullptr

  // ---- weight split prep (all L2-warm afterwards) ----
  wsplit_kernel<<<256, blk, 0, stream>>>(W_v,  wv_hi, wv_lo, 65536, 256);
  wsplit_kernel<<<256, blk, 0, stream>>>(Wq_m, wq_hi, wq_lo, 65536, 256);
  wsplit_kernel<<<256, blk, 0, stream>>>(Wo_m, wo_hi, wo_lo, 65536, 256);
  wsplit_kernel<<<1024, blk, 0, stream>>>(f2W1, w1_hi, w1_lo, 262144, 1024);
  wsplit_kernel<<<1024, blk, 0, stream>>>(f2W2, w2_hi, w2_lo, 262144, 256);

  // ---- big MFMA GEMMs independent of txt chain ----
  // vproj = value @ W_v + b_v (value gathered from feats)
  mgemm<2, 0><<<dim3(532, 2), blk, 0, stream>>>(
      nullptr, nullptr, wv_hi, wv_lo, b_v, buf0, MV, DD, DD, DD, DD, 0, 0,
      feat0, feat1, feat2, feat3);
  // qh = (vis_tokens + vis_pos) @ Wq_m + bq_m
  mgemm<1, 0><<<dim3(532, 2), blk, 0, stream>>>(
      vis_tokens, vis_pos, wq_hi, wq_lo, bq_m, buf1, MV, DD, DD, DD, DD, 0, 0, NOF);

  // ---- txt chain (256 rows, fp32) ----
  gemm_k<32,64,2,4,AM_ADD,EP_BIAS><<<dim3(8,4), blk, 0, stream>>>(
      txt_tokens, txt_pos, W_q, b_q, qb, 256, DD, DD, DD);
  gemm_k<32,64,2,4,AM_PLAIN,EP_BIAS><<<dim3(8,4), blk, 0, stream>>>(
      qb, nullptr, W_off, b_off, offb, 256, DD, DD, DD);
  gemm_k<32,64,2,4,AM_PLAIN,EP_BIAS><<<dim3(8,2), blk, 0, stream>>>(
      qb, nullptr, W_aw, b_aw, awlb, 256, DD, 128, 128);
  softloc_kernel<<<8, blk, 0, stream>>>(awlb, offb, refp, awb, locb);
  sampler_kernel<<<256, blk, 0, stream>>>(buf0, locb, awb, accb);
  gemm_k<32,64,2,4,AM_PLAIN,EP_BIAS><<<dim3(8,4), blk, 0, stream>>>(
      accb, nullptr, W_do, b_do, doutb, 256, DD, DD, DD);
  gemm_k<32,64,2,4,AM_PLAIN,EP_BIAS><<<dim3(8,4), blk, 0, stream>>>(
      doutb, nullptr, W_out, b_out, tattn, 256, DD, DD, DD);
  ln_kernel<<<64, blk, 0, stream>>>(tattn, txt_tokens, ln1_g, ln1_b, tres1, 256);
  gemm_k<32,64,2,4,AM_PLAIN,EP_GELU><<<dim3(8,16), blk, 0, stream>>>(
      tres1, nullptr, f1W1, f1b1, ffh, 256, DD, 1024, 1024);
  gemm_k<32,64,2,4,AM_PLAIN,EP_BIAS><<<dim3(8,4), blk, 0, stream>>>(
      ffh, nullptr, f1W2, f1b2, ffb, 256, 1024, DD, DD);
  ln_kernel<<<64, blk, 0, stream>>>(ffb, tres1, ln2_g, ln2_b, out_txt, 256);

  gemm_k<32,64,2,4,AM_ADD,EP_BIAS><<<dim3(8,4), blk, 0, stream>>>(
      out_txt, txt_pos, Wk_m, bk_m, khb, 256, DD, DD, DD);
  gemm_k<32,64,2,4,AM_ADD,EP_BIAS><<<dim3(8,4), blk, 0, stream>>>(
      out_txt, txt_pos, Wv_m, bv_m, vhb, 256, DD, DD, DD);

  // ---- vli attention + output proj + LN ----
  attn_kernel<<<dim3(532, 8), dim3(512), 0, stream>>>(buf1, khb, vhb, buf2, out_aw);
  mgemm<0, 0><<<dim3(532, 2), blk, 0, stream>>>(
      buf2, nullptr, wo_hi, wo_lo, bo_m, buf0, MV, DD, DD, DD, DD, 0, 0, NOF);
  ln_kernel<<<17000, blk, 0, stream>>>(buf0, vis_tokens, vln1_g, vln1_b, buf1, MV);

  // ---- ffn2: hidden 1024 in 2 chunks of 512; hidden stored bf16 in buf2 ----
  for (int c = 0; c < 2; ++c) {
    mgemm<0, 1><<<dim3(532, 4), blk, 0, stream>>>(
        buf1, nullptr, w1_hi, w1_lo, f2b1 + c * 512, buf2,
        MV, DD, DD, 512, 1024, c * 512, 0, NOF);
    if (c == 0) {
      mgemm<3, 0><<<dim3(532, 2), blk, 0, stream>>>(
          buf2, nullptr, w2_hi, w2_lo, f2b2, buf0,
          MV, 512, 512, DD, DD, 0, 0, NOF);
    } else {
      mgemm<3, 2><<<dim3(532, 2), blk, 0, stream>>>(
          buf2, nullptr, w2_hi, w2_lo, nullptr, buf0,
          MV, 512, 512, DD, DD, 0, 16, NOF);
    }
  }
  ln_kernel<<<17000, blk, 0, stream>>>(buf0, buf1, vln2_g, vln2_b, out_vis, MV);
  #undef NOF
}

// Round 5
// 1287.716 us; speedup vs baseline: 2.1767x; 1.0109x over previous
//
#include <hip/hip_runtime.h>
#include <cstddef>

// ---- problem constants ----
#define DD   256
#define NHH  8
#define HDD  32
#define BB   8
#define LT   32
#define LV   8500   // 6400+1600+400+100

typedef unsigned short u16;
typedef unsigned int   u32;
typedef __attribute__((ext_vector_type(8))) short short8;
typedef __attribute__((ext_vector_type(8))) unsigned short ushort8;
typedef __attribute__((ext_vector_type(4))) float f32x4;

__device__ __forceinline__ float gelu_f(float x) {
  return 0.5f * x * (1.0f + erff(x * 0.70710678118654752440f));
}

// fp32 -> bf16 round-to-nearest-even
__device__ __forceinline__ u16 f2bf(float x) {
  u32 u = __float_as_uint(x);
  u += 0x7FFFu + ((u >> 16) & 1u);
  return (u16)(u >> 16);
}
__device__ __forceinline__ float bf2f(u16 h) { return __uint_as_float((u32)h << 16); }

// async global->LDS, 16B per lane; LDS dest must be wave-uniform base (+lane*16 implicit)
__device__ __forceinline__ void gload16(const u16* g, u16* l) {
  __builtin_amdgcn_global_load_lds(
      (const __attribute__((address_space(1))) void*)g,
      (__attribute__((address_space(3))) void*)l, 16, 0, 0);
}

enum { AM_PLAIN = 0, AM_ADD = 1, AM_FEAT = 2, AM_HI = 3, AM_SPLIT = 4 };
enum { EP_BIAS = 0, EP_GELU = 1, EP_ACC = 2 };

// ======================= fp32 tiled GEMM (small txt-side only) =======================
template<int BM, int BN, int TM, int TN, int AMODE, int EPI>
__launch_bounds__(256)
__global__ void gemm_k(const float* __restrict__ A0, const float* __restrict__ A1,
                       const float* __restrict__ Wt, const float* __restrict__ bias,
                       float* __restrict__ C, int M, int K, int ldw, int ldc)
{
  constexpr int BK = 16;
  __shared__ __align__(16) float As[BK][BM];
  __shared__ __align__(16) float Ws[BK][BN];
  const int tid  = threadIdx.x;
  const int row0 = blockIdx.x * BM;
  const int col0 = blockIdx.y * BN;
  const int tx = tid % (BN / TN);
  const int ty = tid / (BN / TN);
  float acc[TM][TN] = {};

  for (int k0 = 0; k0 < K; k0 += BK) {
    {
      constexpr int AU = BM * BK / 4;
      for (int u = tid; u < AU; u += 256) {
        int m  = u / (BK / 4);
        int kq = (u % (BK / 4)) * 4;
        int grow = row0 + m;
        float4 v = make_float4(0.f, 0.f, 0.f, 0.f);
        if (grow < M) {
          v = *(const float4*)(A0 + (size_t)grow * K + k0 + kq);
          if constexpr (AMODE == AM_ADD) {
            float4 w = *(const float4*)(A1 + (size_t)grow * K + k0 + kq);
            v.x += w.x; v.y += w.y; v.z += w.z; v.w += w.w;
          }
        }
        As[kq + 0][m] = v.x; As[kq + 1][m] = v.y;
        As[kq + 2][m] = v.z; As[kq + 3][m] = v.w;
      }
    }
    {
      constexpr int WU = BK * BN / 4;
      for (int u = tid; u < WU; u += 256) {
        int k  = u / (BN / 4);
        int n4 = (u % (BN / 4)) * 4;
        *(float4*)&Ws[k][n4] =
            *(const float4*)(Wt + (size_t)(k0 + k) * ldw + col0 + n4);
      }
    }
    __syncthreads();

    #pragma unroll
    for (int k = 0; k < BK; ++k) {
      float a[TM], bv[TN];
      #pragma unroll
      for (int i = 0; i < TM; ++i) a[i] = As[k][ty * TM + i];
      #pragma unroll
      for (int j = 0; j < TN; j += 4) {
        float4 t4 = *(const float4*)&Ws[k][tx * TN + j];
        bv[j] = t4.x; bv[j + 1] = t4.y; bv[j + 2] = t4.z; bv[j + 3] = t4.w;
      }
      #pragma unroll
      for (int i = 0; i < TM; ++i)
        #pragma unroll
        for (int j = 0; j < TN; ++j)
          acc[i][j] = fmaf(a[i], bv[j], acc[i][j]);
    }
    __syncthreads();
  }

  #pragma unroll
  for (int i = 0; i < TM; ++i) {
    int r = row0 + ty * TM + i;
    if (r >= M) continue;
    #pragma unroll
    for (int j4 = 0; j4 < TN; j4 += 4) {
      int c = col0 + tx * TN + j4;
      float4 v = make_float4(acc[i][j4], acc[i][j4 + 1], acc[i][j4 + 2], acc[i][j4 + 3]);
      float4 b4 = *(const float4*)(bias + c);
      v.x += b4.x; v.y += b4.y; v.z += b4.z; v.w += b4.w;
      if constexpr (EPI == EP_GELU) {
        v.x = gelu_f(v.x); v.y = gelu_f(v.y); v.z = gelu_f(v.z); v.w = gelu_f(v.w);
      }
      *(float4*)(C + (size_t)r * ldc + c) = v;
    }
  }
}

// ======================= weight split prep =======================
// out[((k>>3)*Nw + n)*8 + (k&7)] = hi/lo bf16 of W[k][n]  (fragment-ready layout)
__global__ void wsplit_kernel(const float* __restrict__ W, u16* __restrict__ hi,
                              u16* __restrict__ lo, int total, int Nw)
{
  int id = blockIdx.x * 256 + threadIdx.x;
  if (id >= total) return;
  int k = id / Nw, n = id - k * Nw;
  float x = W[id];
  u16 h = f2bf(x);
  u16 l = f2bf(x - bf2f(h));
  int o = ((k >> 3) * Nw + n) * 8 + (k & 7);
  hi[o] = h; lo[o] = l;
}

// ======================= split-bf16 MFMA GEMM =======================
// C[M x N] = epi( A[M x K] @ W[K x Nw (window wcol0..)] + bias )
// AMODE: 1 add two fp32 (in-kernel split), 2 feat-gather fp32 (in-kernel split),
//        3 bf16 hi-only via global_load_lds (2-term), 4 bf16 hi+lo planes via
//        global_load_lds (3-term, Ap=hi plane, A1p=lo plane; lda in u16 units)
// EPI:   0 +bias -> fp32, 1 +bias,gelu -> bf16, 2 accumulate into fp32 C (no bias)
// Tile 128x128xBK32, 4 waves x (64x64).
template<int AMODE, int EPI>
__global__ __launch_bounds__(256) void mgemm(
    const void* __restrict__ Ap, const void* __restrict__ A1p,
    const u16* __restrict__ Whi, const u16* __restrict__ Wlo,
    const float* __restrict__ bias, void* __restrict__ Cp,
    int M, int K, int lda, int ldc, int Nw, int wcol0, int ks0,
    const float* __restrict__ f0, const float* __restrict__ f1,
    const float* __restrict__ f2, const float* __restrict__ f3)
{
  constexpr bool GL = (AMODE >= 3);
  constexpr int SMEM_U16 = GL ? (AMODE == AM_SPLIT ? 16384 : 8192) : 8256;
  __shared__ __align__(16) u16 smem[SMEM_U16];
  const int tid  = threadIdx.x;
  const int lane = tid & 63;
  const int w    = tid >> 6;
  const int wr   = w >> 1, wc = w & 1;
  const int row0  = blockIdx.x * 128;
  const int colC0 = blockIdx.y * 128;
  f32x4 acc[4][4] = {};
  const int nk = K >> 5;

  if constexpr (GL) {
    // ---- pre-split bf16 A, async staged, 2-deep double buffer ----
    const u16* Ah = (const u16*)Ap;
    const u16* Al = (const u16*)A1p;
    auto stage = [&](int t, int buf) {
      #pragma unroll
      for (int p = 0; p < 2; ++p) {
        int i = w + p * 4;                       // 8 x 1KB loads, 2 per wave
        int r = row0 + i * 16 + (lane >> 2);
        if (r >= M) r = M - 1;
        size_t goff = (size_t)r * lda + t * 32 + (lane & 3) * 8;
        gload16(Ah + goff, &smem[buf * 4096 + i * 512]);
        if constexpr (AMODE == AM_SPLIT)
          gload16(Al + goff, &smem[8192 + buf * 4096 + i * 512]);
      }
    };
    stage(0, 0);
    __syncthreads();
    for (int kt = 0; kt < nk; ++kt) {
      const int cur = kt & 1;
      if (kt + 1 < nk) stage(kt + 1, cur ^ 1);
      const int slot = lane >> 4;
      const int lrow = lane & 15;
      short8 ah[4], al[4], bh[4], bl[4];
      #pragma unroll
      for (int m = 0; m < 4; ++m) {
        int off = cur * 4096 + (((wr * 64 + m * 16 + lrow) << 2) + slot) * 8;
        ah[m] = *(const short8*)&smem[off];
        if constexpr (AMODE == AM_SPLIT) al[m] = *(const short8*)&smem[8192 + off];
      }
      #pragma unroll
      for (int n = 0; n < 4; ++n) {
        size_t off = ((size_t)((ks0 + kt) * 4 + slot) * Nw + wcol0 + colC0 + wc * 64 + n * 16 + lrow) * 8;
        bh[n] = *(const short8*)(Whi + off);
        bl[n] = *(const short8*)(Wlo + off);
      }
      #pragma unroll
      for (int m = 0; m < 4; ++m)
        #pragma unroll
        for (int n = 0; n < 4; ++n) {
          acc[m][n] = __builtin_amdgcn_mfma_f32_16x16x32_bf16(ah[m], bh[n], acc[m][n], 0, 0, 0);
          acc[m][n] = __builtin_amdgcn_mfma_f32_16x16x32_bf16(ah[m], bl[n], acc[m][n], 0, 0, 0);
          if constexpr (AMODE == AM_SPLIT)
            acc[m][n] = __builtin_amdgcn_mfma_f32_16x16x32_bf16(al[m], bh[n], acc[m][n], 0, 0, 0);
        }
      __syncthreads();
    }
  } else {
    // ---- fp32 A, in-kernel split; padded slot-major layout [slot][row(+pad)][8] ----
    u16* Ahi = smem;
    u16* Alo = smem + 4128;
    for (int kt = 0; kt < nk; ++kt) {
      #pragma unroll
      for (int p = 0; p < 4; ++p) {
        int j = tid + p * 256;
        int row, f4;
        if constexpr (AMODE == AM_FEAT) { f4 = j >> 7; row = j & 127; }
        else                            { row = j >> 3; f4 = j & 7; }
        int gr = row0 + row;
        float4 v = make_float4(0.f, 0.f, 0.f, 0.f);
        if (gr < M) {
          if constexpr (AMODE == AM_FEAT) {
            int b = gr / LV;
            int s = gr - b * LV;
            int l = (s >= 8400) ? 3 : (s >= 8000) ? 2 : (s >= 6400) ? 1 : 0;
            const float* fp = (l == 0) ? f0 : (l == 1) ? f1 : (l == 2) ? f2 : f3;
            const int hw = (l == 0) ? 6400 : (l == 1) ? 1600 : (l == 2) ? 400 : 100;
            const int st = (l == 0) ? 0 : (l == 1) ? 6400 : (l == 2) ? 8000 : 8400;
            const float* base = fp + ((size_t)b * DD + (kt * 32 + f4 * 4)) * hw + (s - st);
            v.x = base[0];
            v.y = base[(size_t)hw];
            v.z = base[2 * (size_t)hw];
            v.w = base[3 * (size_t)hw];
          } else {
            const float* Af = (const float*)Ap;
            v = *(const float4*)(Af + (size_t)gr * lda + kt * 32 + f4 * 4);
            if constexpr (AMODE == AM_ADD) {
              float4 u2 = *(const float4*)((const float*)A1p + (size_t)gr * lda + kt * 32 + f4 * 4);
              v.x += u2.x; v.y += u2.y; v.z += u2.z; v.w += u2.w;
            }
          }
        }
        int slot = f4 >> 1, half = f4 & 1;
        int off = (slot * 129 + row) * 8 + half * 4;
        u16 h0 = f2bf(v.x), h1 = f2bf(v.y), h2 = f2bf(v.z), h3 = f2bf(v.w);
        uint2 hp; hp.x = (u32)h0 | ((u32)h1 << 16); hp.y = (u32)h2 | ((u32)h3 << 16);
        *(uint2*)&Ahi[off] = hp;
        u16 l0 = f2bf(v.x - bf2f(h0)), l1 = f2bf(v.y - bf2f(h1));
        u16 l2 = f2bf(v.z - bf2f(h2)), l3 = f2bf(v.w - bf2f(h3));
        uint2 lp; lp.x = (u32)l0 | ((u32)l1 << 16); lp.y = (u32)l2 | ((u32)l3 << 16);
        *(uint2*)&Alo[off] = lp;
      }
      __syncthreads();

      const int slot = lane >> 4;
      const int lrow = lane & 15;
      short8 ah[4], al[4], bh[4], bl[4];
      #pragma unroll
      for (int m = 0; m < 4; ++m) {
        int off = (slot * 129 + wr * 64 + m * 16 + lrow) * 8;
        ah[m] = *(const short8*)&Ahi[off];
        al[m] = *(const short8*)&Alo[off];
      }
      #pragma unroll
      for (int n = 0; n < 4; ++n) {
        size_t off = ((size_t)((ks0 + kt) * 4 + slot) * Nw + wcol0 + colC0 + wc * 64 + n * 16 + lrow) * 8;
        bh[n] = *(const short8*)(Whi + off);
        bl[n] = *(const short8*)(Wlo + off);
      }
      #pragma unroll
      for (int m = 0; m < 4; ++m)
        #pragma unroll
        for (int n = 0; n < 4; ++n) {
          acc[m][n] = __builtin_amdgcn_mfma_f32_16x16x32_bf16(ah[m], bh[n], acc[m][n], 0, 0, 0);
          acc[m][n] = __builtin_amdgcn_mfma_f32_16x16x32_bf16(ah[m], bl[n], acc[m][n], 0, 0, 0);
          acc[m][n] = __builtin_amdgcn_mfma_f32_16x16x32_bf16(al[m], bh[n], acc[m][n], 0, 0, 0);
        }
      __syncthreads();
    }
  }

  // epilogue: C/D frag mapping col=lane&15, row=(lane>>4)*4+j  [m89-verified]
  const int lrow = lane & 15;
  #pragma unroll
  for (int m = 0; m < 4; ++m) {
    #pragma unroll
    for (int j = 0; j < 4; ++j) {
      int r = row0 + wr * 64 + m * 16 + ((lane >> 4) << 2) + j;
      if (r >= M) continue;
      #pragma unroll
      for (int n = 0; n < 4; ++n) {
        int c = colC0 + wc * 64 + n * 16 + lrow;
        float v = acc[m][n][j];
        if constexpr (EPI == EP_BIAS) {
          ((float*)Cp)[(size_t)r * ldc + c] = v + bias[c];
        } else if constexpr (EPI == EP_GELU) {
          ((u16*)Cp)[(size_t)r * ldc + c] = f2bf(gelu_f(v + bias[c]));
        } else {
          ((float*)Cp)[(size_t)r * ldc + c] += v;
        }
      }
    }
  }
}

// ======================= LayerNorm kernels =======================
__device__ __forceinline__ float4 ln_core(float4 x, const float* g, const float* bta, int lane) {
  float s  = x.x + x.y + x.z + x.w;
  float s2 = x.x * x.x + x.y * x.y + x.z * x.z + x.w * x.w;
  #pragma unroll
  for (int m = 1; m < 64; m <<= 1) {
    s  += __shfl_xor(s, m);
    s2 += __shfl_xor(s2, m);
  }
  float mean = s * (1.0f / 256.0f);
  float var  = s2 * (1.0f / 256.0f) - mean * mean;
  float rstd = rsqrtf(var + 1e-5f);
  float4 gg = *(const float4*)(g + lane * 4);
  float4 bb = *(const float4*)(bta + lane * 4);
  float4 o;
  o.x = (x.x - mean) * rstd * gg.x + bb.x;
  o.y = (x.y - mean) * rstd * gg.y + bb.y;
  o.z = (x.z - mean) * rstd * gg.z + bb.z;
  o.w = (x.w - mean) * rstd * gg.w + bb.w;
  return o;
}

__global__ void ln_kernel(const float* __restrict__ X, const float* __restrict__ R,
                          const float* __restrict__ g, const float* __restrict__ bta,
                          float* __restrict__ O, int M)
{
  int row  = blockIdx.x * 4 + (threadIdx.x >> 6);
  int lane = threadIdx.x & 63;
  if (row >= M) return;
  size_t base = (size_t)row * DD + lane * 4;
  float4 x = *(const float4*)(X + base);
  float4 r = *(const float4*)(R + base);
  x.x += r.x; x.y += r.y; x.z += r.z; x.w += r.w;
  float4 o = ln_core(x, g, bta, lane);
  *(float4*)(O + base) = o;
}

// LN(X + R) -> split bf16 hi/lo planes
__global__ void ln_vis1(const float* __restrict__ X, const float* __restrict__ R,
                        const float* __restrict__ g, const float* __restrict__ bta,
                        u16* __restrict__ Oh, u16* __restrict__ Ol, int M)
{
  int row  = blockIdx.x * 4 + (threadIdx.x >> 6);
  int lane = threadIdx.x & 63;
  if (row >= M) return;
  size_t base = (size_t)row * DD + lane * 4;
  float4 x = *(const float4*)(X + base);
  float4 r = *(const float4*)(R + base);
  x.x += r.x; x.y += r.y; x.z += r.z; x.w += r.w;
  float4 o = ln_core(x, g, bta, lane);
  u16 h0 = f2bf(o.x), h1 = f2bf(o.y), h2 = f2bf(o.z), h3 = f2bf(o.w);
  uint2 hp; hp.x = (u32)h0 | ((u32)h1 << 16); hp.y = (u32)h2 | ((u32)h3 << 16);
  *(uint2*)(Oh + base) = hp;
  u16 l0 = f2bf(o.x - bf2f(h0)), l1 = f2bf(o.y - bf2f(h1));
  u16 l2 = f2bf(o.z - bf2f(h2)), l3 = f2bf(o.w - bf2f(h3));
  uint2 lp; lp.x = (u32)l0 | ((u32)l1 << 16); lp.y = (u32)l2 | ((u32)l3 << 16);
  *(uint2*)(Ol + base) = lp;
}

// LN(X + (Rh+Rl)) -> fp32
__global__ void ln_vis2(const float* __restrict__ X, const u16* __restrict__ Rh,
                        const u16* __restrict__ Rl, const float* __restrict__ g,
                        const float* __restrict__ bta, float* __restrict__ O, int M)
{
  int row  = blockIdx.x * 4 + (threadIdx.x >> 6);
  int lane = threadIdx.x & 63;
  if (row >= M) return;
  size_t base = (size_t)row * DD + lane * 4;
  float4 x = *(const float4*)(X + base);
  uint2 hp = *(const uint2*)(Rh + base);
  uint2 lp = *(const uint2*)(Rl + base);
  x.x += bf2f((u16)hp.x) + bf2f((u16)lp.x);
  x.y += bf2f((u16)(hp.x >> 16)) + bf2f((u16)(lp.x >> 16));
  x.z += bf2f((u16)hp.y) + bf2f((u16)lp.y);
  x.w += bf2f((u16)(hp.y >> 16)) + bf2f((u16)(lp.y >> 16));
  float4 o = ln_core(x, g, bta, lane);
  *(float4*)(O + base) = o;
}

// ======================= deformable softmax+loc =======================
__global__ void softloc_kernel(const float* __restrict__ awl, const float* __restrict__ offb,
                               const float* __restrict__ refp, float* __restrict__ aw,
                               float* __restrict__ loc)
{
  int idx = blockIdx.x * 256 + threadIdx.x;
  if (idx >= BB * LT * NHH) return;
  int h   = idx & 7;
  int row = idx >> 3;
  float v[16]; float mx = -1e30f;
  #pragma unroll
  for (int i = 0; i < 16; ++i) { v[i] = awl[row * 128 + h * 16 + i]; mx = fmaxf(mx, v[i]); }
  float sum = 0.f;
  #pragma unroll
  for (int i = 0; i < 16; ++i) { v[i] = expf(v[i] - mx); sum += v[i]; }
  float inv = 1.0f / sum;
  #pragma unroll
  for (int i = 0; i < 16; ++i) aw[row * 128 + h * 16 + i] = v[i] * inv;
  const float invn[4] = {1.f / 80.f, 1.f / 40.f, 1.f / 20.f, 1.f / 10.f};
  #pragma unroll
  for (int l = 0; l < 4; ++l) {
    float rx = refp[(row * 4 + l) * 2 + 0];
    float ry = refp[(row * 4 + l) * 2 + 1];
    #pragma unroll
    for (int p = 0; p < 4; ++p) {
      int o = row * 256 + h * 32 + l * 8 + p * 2;
      loc[o + 0] = rx + offb[o + 0] * invn[l];
      loc[o + 1] = ry + offb[o + 1] * invn[l];
    }
  }
}

// ======================= deformable sampler =======================
__global__ void sampler_kernel(const float* __restrict__ vproj, const float* __restrict__ loc,
                               const float* __restrict__ aw, float* __restrict__ acc)
{
  int row = blockIdx.x;          // b*32 + q
  int t   = threadIdx.x;
  int h   = t >> 5, hd = t & 31;
  int b   = row >> 5;
  const float* vb = vproj + (size_t)b * LV * DD;
  const int Hs[4] = {80, 40, 20, 10};
  const int st[4] = {0, 6400, 8000, 8400};
  float a = 0.f;
  #pragma unroll
  for (int l = 0; l < 4; ++l) {
    const int Wl = Hs[l], Hl = Hs[l];
    #pragma unroll
    for (int p = 0; p < 4; ++p) {
      int o = row * 256 + h * 32 + l * 8 + p * 2;
      float lx  = loc[o + 0];
      float ly  = loc[o + 1];
      float wgt = aw[row * 128 + h * 16 + l * 4 + p];
      float x = lx * (float)Wl - 0.5f;
      float y = ly * (float)Hl - 0.5f;
      float x0f = floorf(x), y0f = floorf(y);
      float fx = x - x0f, fy = y - y0f;
      int x0 = (int)x0f, y0 = (int)y0f;
      #pragma unroll
      for (int dy = 0; dy < 2; ++dy) {
        #pragma unroll
        for (int dx = 0; dx < 2; ++dx) {
          int xi = x0 + dx, yi = y0 + dy;
          float w2 = (dx ? fx : 1.f - fx) * (dy ? fy : 1.f - fy);
          if (xi >= 0 && xi < Wl && yi >= 0 && yi < Hl) {
            a = fmaf(wgt * w2, vb[(size_t)(st[l] + yi * Wl + xi) * DD + h * 32 + hd], a);
          }
        }
      }
    }
  }
  acc[(size_t)row * DD + t] = a;
}

// ======================= cross attention (32 keys), no-LDS =======================
// Block = 512 thr = 16 query rows x 32 lanes; lane = (head h=l>>2, part=l&3) owns 8 dims.
// K/V read direct from global (L1/L2-served broadcast; 512 KB total, stays hot).
// Output mo written as split bf16 hi/lo planes (consumed by AM_SPLIT mgemm).
__global__ __launch_bounds__(512)
void attn_kernel(const float* __restrict__ qh, const float* __restrict__ kh,
                 const float* __restrict__ vh, u16* __restrict__ mo_hi,
                 u16* __restrict__ mo_lo, float* __restrict__ awout)
{
  const int b  = blockIdx.y;
  const int rl = threadIdx.x >> 5;
  const int l  = threadIdx.x & 31;
  const int h  = l >> 2;
  const int part = l & 3;
  const int s  = blockIdx.x * 16 + rl;
  if (s >= LV) return;
  const size_t row = (size_t)b * LV + s;
  const int c0 = h * 32 + part * 8;
  const float scale = 0.17677669529663687f;  // 1/sqrt(32)
  const float* Kb = kh + (size_t)b * 32 * DD;
  const float* Vb = vh + (size_t)b * 32 * DD;

  float q[8];
  {
    const float4* qp = (const float4*)(qh + row * DD + c0);
    float4 a = qp[0], c = qp[1];
    q[0]=a.x; q[1]=a.y; q[2]=a.z; q[3]=a.w; q[4]=c.x; q[5]=c.y; q[6]=c.z; q[7]=c.w;
  }

  float sc[32]; float mx = -1e30f;
  #pragma unroll
  for (int k = 0; k < 32; ++k) {
    const float4* kp = (const float4*)(Kb + k * DD + c0);
    float4 a = kp[0], c = kp[1];
    float d = 0.f;
    d = fmaf(q[0], a.x, d); d = fmaf(q[1], a.y, d); d = fmaf(q[2], a.z, d); d = fmaf(q[3], a.w, d);
    d = fmaf(q[4], c.x, d); d = fmaf(q[5], c.y, d); d = fmaf(q[6], c.z, d); d = fmaf(q[7], c.w, d);
    d += __shfl_xor(d, 1);
    d += __shfl_xor(d, 2);
    sc[k] = d * scale;
    mx = fmaxf(mx, sc[k]);
  }
  float sum = 0.f;
  #pragma unroll
  for (int k = 0; k < 32; ++k) { sc[k] = expf(sc[k] - mx); sum += sc[k]; }
  const float inv = 1.0f / sum;
  #pragma unroll
  for (int k = 0; k < 32; ++k) sc[k] *= inv;

  float o[8] = {};
  #pragma unroll
  for (int k = 0; k < 32; ++k) {
    const float4* vp = (const float4*)(Vb + k * DD + c0);
    float4 a = vp[0], c = vp[1];
    const float pk = sc[k];
    o[0] = fmaf(pk, a.x, o[0]); o[1] = fmaf(pk, a.y, o[1]);
    o[2] = fmaf(pk, a.z, o[2]); o[3] = fmaf(pk, a.w, o[3]);
    o[4] = fmaf(pk, c.x, o[4]); o[5] = fmaf(pk, c.y, o[5]);
    o[6] = fmaf(pk, c.z, o[6]); o[7] = fmaf(pk, c.w, o[7]);
  }
  {
    u16 hh[8], ll[8];
    #pragma unroll
    for (int j = 0; j < 8; ++j) {
      hh[j] = f2bf(o[j]);
      ll[j] = f2bf(o[j] - bf2f(hh[j]));
    }
    uint4 hp, lp;
    hp.x = (u32)hh[0] | ((u32)hh[1] << 16); hp.y = (u32)hh[2] | ((u32)hh[3] << 16);
    hp.z = (u32)hh[4] | ((u32)hh[5] << 16); hp.w = (u32)hh[6] | ((u32)hh[7] << 16);
    lp.x = (u32)ll[0] | ((u32)ll[1] << 16); lp.y = (u32)ll[2] | ((u32)ll[3] << 16);
    lp.z = (u32)ll[4] | ((u32)ll[5] << 16); lp.w = (u32)ll[6] | ((u32)ll[7] << 16);
    *(uint4*)(mo_hi + row * DD + c0) = hp;
    *(uint4*)(mo_lo + row * DD + c0) = lp;
  }
  #pragma unroll
  for (int k = 0; k < 32; ++k) {
    float v = sc[k];
    v += __shfl_xor(v, 4);
    v += __shfl_xor(v, 8);
    v += __shfl_xor(v, 16);
    if (h == 0 && (k >> 3) == part) awout[row * 32 + k] = v * 0.125f;
  }
}

extern "C" void kernel_launch(void* const* d_in, const int* in_sizes, int n_in,
                              void* d_out, int out_size, void* d_ws, size_t ws_size,
                              hipStream_t stream)
{
  const float* txt_tokens = (const float*)d_in[0];
  const float* vis_tokens = (const float*)d_in[1];
  const float* feat0 = (const float*)d_in[2];
  const float* feat1 = (const float*)d_in[3];
  const float* feat2 = (const float*)d_in[4];
  const float* feat3 = (const float*)d_in[5];
  const float* refp    = (const float*)d_in[8];
  const float* txt_pos = (const float*)d_in[9];
  const float* vis_pos = (const float*)d_in[10];
  const float* W_off = (const float*)d_in[11]; const float* b_off = (const float*)d_in[12];
  const float* W_aw  = (const float*)d_in[13]; const float* b_aw  = (const float*)d_in[14];
  const float* W_v   = (const float*)d_in[15]; const float* b_v   = (const float*)d_in[16];
  const float* W_do  = (const float*)d_in[17]; const float* b_do  = (const float*)d_in[18];
  const float* W_q   = (const float*)d_in[19]; const float* b_q   = (const float*)d_in[20];
  const float* W_out = (const float*)d_in[21]; const float* b_out = (const float*)d_in[22];
  const float* ln1_g = (const float*)d_in[23]; const float* ln1_b = (const float*)d_in[24];
  const float* ln2_g = (const float*)d_in[25]; const float* ln2_b = (const float*)d_in[26];
  const float* f1W1  = (const float*)d_in[27]; const float* f1b1  = (const float*)d_in[28];
  const float* f1W2  = (const float*)d_in[29]; const float* f1b2  = (const float*)d_in[30];
  const float* Wq_m  = (const float*)d_in[31]; const float* bq_m  = (const float*)d_in[32];
  const float* Wk_m  = (const float*)d_in[33]; const float* bk_m  = (const float*)d_in[34];
  const float* Wv_m  = (const float*)d_in[35]; const float* bv_m  = (const float*)d_in[36];
  const float* Wo_m  = (const float*)d_in[37]; const float* bo_m  = (const float*)d_in[38];
  const float* vln1_g = (const float*)d_in[39]; const float* vln1_b = (const float*)d_in[40];
  const float* vln2_g = (const float*)d_in[41]; const float* vln2_b = (const float*)d_in[42];
  const float* f2W1  = (const float*)d_in[43]; const float* f2b1  = (const float*)d_in[44];
  const float* f2W2  = (const float*)d_in[45]; const float* f2b2  = (const float*)d_in[46];

  const int MV = BB * LV;  // 68000
  float* ws = (float*)d_ws;
  const size_t BIG = (size_t)MV * DD;  // 17,408,000 floats
  float* buf0 = ws;                    // vproj -> moproj out -> ffn2 acc
  float* buf1 = ws + BIG;              // qh -> ln1 split planes
  float* buf2 = ws + 2 * BIG;          // mo split planes -> ffn2 hidden (bf16)
  float* sm   = ws + 3 * BIG;
  float* qb    = sm;              // 65536
  float* offb  = qb + 65536;
  float* awlb  = offb + 65536;    // 32768
  float* awb   = awlb + 32768;    // 32768
  float* locb  = awb + 32768;     // 65536
  float* accb  = locb + 65536;    // 65536
  float* doutb = accb + 65536;    // 65536
  float* tattn = doutb + 65536;   // 65536
  float* tres1 = tattn + 65536;   // 65536
  float* ffh   = tres1 + 65536;   // 262144
  float* ffb   = ffh + 262144;    // 65536
  float* khb   = ffb + 65536;     // 65536
  float* vhb   = khb + 65536;     // 65536
  // split-weight buffers (u16)
  u16* wsp   = (u16*)(vhb + 65536);
  u16* wv_hi = wsp;               u16* wv_lo = wv_hi + 65536;
  u16* wq_hi = wv_lo + 65536;     u16* wq_lo = wq_hi + 65536;
  u16* wo_hi = wq_lo + 65536;     u16* wo_lo = wo_hi + 65536;
  u16* w1_hi = wo_lo + 65536;     u16* w1_lo = w1_hi + 262144;
  u16* w2_hi = w1_lo + 262144;    u16* w2_lo = w2_hi + 262144;

  // aliased big-buffer views
  u16* mo_hi = (u16*)buf2;  u16* mo_lo = mo_hi + BIG;
  u16* ln_hi = (u16*)buf1;  u16* ln_lo = ln_hi + BIG;
  u16* hid   = (u16*)buf2;  // ffn2a out, overwrites mo planes (dead by then)

  float* out_txt = (float*)d_out;                       // [8,32,256]
  float* out_vis = out_txt + (size_t)BB * LT * DD;      // [8,8500,256]
  float* out_aw  = out_vis + BIG;                       // [8,8500,32]

  dim3 blk(256);
  #define NOF nullptr, nullptr, nullptr, nullptr

  // ---- weight split prep ----
  wsplit_kernel<<<256, blk, 0, stream>>>(W_v,  wv_hi, wv_lo, 65536, 256);
  wsplit_kernel<<<256, blk, 0, stream>>>(Wq_m, wq_hi, wq_lo, 65536, 256);
  wsplit_kernel<<<256, blk, 0, stream>>>(Wo_m, wo_hi, wo_lo, 65536, 256);
  wsplit_kernel<<<1024, blk, 0, stream>>>(f2W1, w1_hi, w1_lo, 262144, 1024);
  wsplit_kernel<<<1024, blk, 0, stream>>>(f2W2, w2_hi, w2_lo, 262144, 256);

  // ---- big MFMA GEMMs independent of txt chain ----
  mgemm<AM_FEAT, EP_BIAS><<<dim3(532, 2), blk, 0, stream>>>(
      nullptr, nullptr, wv_hi, wv_lo, b_v, buf0, MV, DD, DD, DD, DD, 0, 0,
      feat0, feat1, feat2, feat3);
  mgemm<AM_ADD, EP_BIAS><<<dim3(532, 2), blk, 0, stream>>>(
      vis_tokens, vis_pos, wq_hi, wq_lo, bq_m, buf1, MV, DD, DD, DD, DD, 0, 0, NOF);

  // ---- txt chain (256 rows, fp32) ----
  gemm_k<32,64,2,4,AM_ADD,EP_BIAS><<<dim3(8,4), blk, 0, stream>>>(
      txt_tokens, txt_pos, W_q, b_q, qb, 256, DD, DD, DD);
  gemm_k<32,64,2,4,AM_PLAIN,EP_BIAS><<<dim3(8,4), blk, 0, stream>>>(
      qb, nullptr, W_off, b_off, offb, 256, DD, DD, DD);
  gemm_k<32,64,2,4,AM_PLAIN,EP_BIAS><<<dim3(8,2), blk, 0, stream>>>(
      qb, nullptr, W_aw, b_aw, awlb, 256, DD, 128, 128);
  softloc_kernel<<<8, blk, 0, stream>>>(awlb, offb, refp, awb, locb);
  sampler_kernel<<<256, blk, 0, stream>>>(buf0, locb, awb, accb);
  gemm_k<32,64,2,4,AM_PLAIN,EP_BIAS><<<dim3(8,4), blk, 0, stream>>>(
      accb, nullptr, W_do, b_do, doutb, 256, DD, DD, DD);
  gemm_k<32,64,2,4,AM_PLAIN,EP_BIAS><<<dim3(8,4), blk, 0, stream>>>(
      doutb, nullptr, W_out, b_out, tattn, 256, DD, DD, DD);
  ln_kernel<<<64, blk, 0, stream>>>(tattn, txt_tokens, ln1_g, ln1_b, tres1, 256);
  gemm_k<32,64,2,4,AM_PLAIN,EP_GELU><<<dim3(8,16), blk, 0, stream>>>(
      tres1, nullptr, f1W1, f1b1, ffh, 256, DD, 1024, 1024);
  gemm_k<32,64,2,4,AM_PLAIN,EP_BIAS><<<dim3(8,4), blk, 0, stream>>>(
      ffh, nullptr, f1W2, f1b2, ffb, 256, 1024, DD, DD);
  ln_kernel<<<64, blk, 0, stream>>>(ffb, tres1, ln2_g, ln2_b, out_txt, 256);

  gemm_k<32,64,2,4,AM_ADD,EP_BIAS><<<dim3(8,4), blk, 0, stream>>>(
      out_txt, txt_pos, Wk_m, bk_m, khb, 256, DD, DD, DD);
  gemm_k<32,64,2,4,AM_ADD,EP_BIAS><<<dim3(8,4), blk, 0, stream>>>(
      out_txt, txt_pos, Wv_m, bv_m, vhb, 256, DD, DD, DD);

  // ---- vli attention + output proj + LN ----
  attn_kernel<<<dim3(532, 8), dim3(512), 0, stream>>>(buf1, khb, vhb, mo_hi, mo_lo, out_aw);
  mgemm<AM_SPLIT, EP_BIAS><<<dim3(532, 2), blk, 0, stream>>>(
      mo_hi, mo_lo, wo_hi, wo_lo, bo_m, buf0, MV, DD, 256, DD, DD, 0, 0, NOF);
  ln_vis1<<<17000, blk, 0, stream>>>(buf0, vis_tokens, vln1_g, vln1_b, ln_hi, ln_lo, MV);

  // ---- ffn2: hidden 1024 in 2 chunks of 512; hidden bf16 in buf2 ----
  for (int c = 0; c < 2; ++c) {
    mgemm<AM_SPLIT, EP_GELU><<<dim3(532, 4), blk, 0, stream>>>(
        ln_hi, ln_lo, w1_hi, w1_lo, f2b1 + c * 512, hid,
        MV, DD, 256, 512, 1024, c * 512, 0, NOF);
    if (c == 0) {
      mgemm<AM_HI, EP_BIAS><<<dim3(532, 2), blk, 0, stream>>>(
          hid, nullptr, w2_hi, w2_lo, f2b2, buf0,
          MV, 512, 512, DD, DD, 0, 0, NOF);
    } else {
      mgemm<AM_HI, EP_ACC><<<dim3(532, 2), blk, 0, stream>>>(
          hid, nullptr, w2_hi, w2_lo, nullptr, buf0,
          MV, 512, 512, DD, DD, 0, 16, NOF);
    }
  }
  ln_vis2<<<17000, blk, 0, stream>>>(buf0, ln_hi, ln_lo, vln2_g, vln2_b, out_vis, MV);
  #undef NOF
}

// Round 6
// 1182.749 us; speedup vs baseline: 2.3698x; 1.0887x over previous
//
#include <hip/hip_runtime.h>
#include <cstddef>

// ---- problem constants ----
#define DD   256
#define NHH  8
#define HDD  32
#define BB   8
#define LT   32
#define LV   8500   // 6400+1600+400+100

typedef unsigned short u16;
typedef unsigned int   u32;
typedef __attribute__((ext_vector_type(8))) short short8;
typedef __attribute__((ext_vector_type(8))) unsigned short ushort8;
typedef __attribute__((ext_vector_type(4))) float f32x4;

__device__ __forceinline__ float gelu_f(float x) {
  return 0.5f * x * (1.0f + erff(x * 0.70710678118654752440f));
}

// fp32 -> bf16 round-to-nearest-even
__device__ __forceinline__ u16 f2bf(float x) {
  u32 u = __float_as_uint(x);
  u += 0x7FFFu + ((u >> 16) & 1u);
  return (u16)(u >> 16);
}
__device__ __forceinline__ float bf2f(u16 h) { return __uint_as_float((u32)h << 16); }

// async global->LDS, 16B per lane; LDS dest must be wave-uniform base (+lane*16 implicit)
__device__ __forceinline__ void gload16(const u16* g, u16* l) {
  __builtin_amdgcn_global_load_lds(
      (const __attribute__((address_space(1))) void*)g,
      (__attribute__((address_space(3))) void*)l, 16, 0, 0);
}

enum { AM_PLAIN = 0, AM_ADD = 1, AM_FEAT = 2, AM_HI = 3, AM_SPLIT = 4 };
enum { EP_BIAS = 0, EP_GELU = 1, EP_ACC = 2 };

// ======================= fp32 tiled GEMM (small txt-side only) =======================
template<int BM, int BN, int TM, int TN, int AMODE, int EPI>
__launch_bounds__(256)
__global__ void gemm_k(const float* __restrict__ A0, const float* __restrict__ A1,
                       const float* __restrict__ Wt, const float* __restrict__ bias,
                       float* __restrict__ C, int M, int K, int ldw, int ldc)
{
  constexpr int BK = 16;
  __shared__ __align__(16) float As[BK][BM];
  __shared__ __align__(16) float Ws[BK][BN];
  const int tid  = threadIdx.x;
  const int row0 = blockIdx.x * BM;
  const int col0 = blockIdx.y * BN;
  const int tx = tid % (BN / TN);
  const int ty = tid / (BN / TN);
  float acc[TM][TN] = {};

  for (int k0 = 0; k0 < K; k0 += BK) {
    {
      constexpr int AU = BM * BK / 4;
      for (int u = tid; u < AU; u += 256) {
        int m  = u / (BK / 4);
        int kq = (u % (BK / 4)) * 4;
        int grow = row0 + m;
        float4 v = make_float4(0.f, 0.f, 0.f, 0.f);
        if (grow < M) {
          v = *(const float4*)(A0 + (size_t)grow * K + k0 + kq);
          if constexpr (AMODE == AM_ADD) {
            float4 w = *(const float4*)(A1 + (size_t)grow * K + k0 + kq);
            v.x += w.x; v.y += w.y; v.z += w.z; v.w += w.w;
          }
        }
        As[kq + 0][m] = v.x; As[kq + 1][m] = v.y;
        As[kq + 2][m] = v.z; As[kq + 3][m] = v.w;
      }
    }
    {
      constexpr int WU = BK * BN / 4;
      for (int u = tid; u < WU; u += 256) {
        int k  = u / (BN / 4);
        int n4 = (u % (BN / 4)) * 4;
        *(float4*)&Ws[k][n4] =
            *(const float4*)(Wt + (size_t)(k0 + k) * ldw + col0 + n4);
      }
    }
    __syncthreads();

    #pragma unroll
    for (int k = 0; k < BK; ++k) {
      float a[TM], bv[TN];
      #pragma unroll
      for (int i = 0; i < TM; ++i) a[i] = As[k][ty * TM + i];
      #pragma unroll
      for (int j = 0; j < TN; j += 4) {
        float4 t4 = *(const float4*)&Ws[k][tx * TN + j];
        bv[j] = t4.x; bv[j + 1] = t4.y; bv[j + 2] = t4.z; bv[j + 3] = t4.w;
      }
      #pragma unroll
      for (int i = 0; i < TM; ++i)
        #pragma unroll
        for (int j = 0; j < TN; ++j)
          acc[i][j] = fmaf(a[i], bv[j], acc[i][j]);
    }
    __syncthreads();
  }

  #pragma unroll
  for (int i = 0; i < TM; ++i) {
    int r = row0 + ty * TM + i;
    if (r >= M) continue;
    #pragma unroll
    for (int j4 = 0; j4 < TN; j4 += 4) {
      int c = col0 + tx * TN + j4;
      float4 v = make_float4(acc[i][j4], acc[i][j4 + 1], acc[i][j4 + 2], acc[i][j4 + 3]);
      float4 b4 = *(const float4*)(bias + c);
      v.x += b4.x; v.y += b4.y; v.z += b4.z; v.w += b4.w;
      if constexpr (EPI == EP_GELU) {
        v.x = gelu_f(v.x); v.y = gelu_f(v.y); v.z = gelu_f(v.z); v.w = gelu_f(v.w);
      }
      *(float4*)(C + (size_t)r * ldc + c) = v;
    }
  }
}

// ======================= weight split prep (all 5 weights, one launch) =======================
// out[((k>>3)*Nw + n)*8 + (k&7)] = hi/lo bf16 of W[k][n]  (fragment-ready layout)
__global__ void wsplit_all(const float* __restrict__ Wv, const float* __restrict__ Wq,
                           const float* __restrict__ Wo, const float* __restrict__ W1,
                           const float* __restrict__ W2,
                           u16* __restrict__ wv_hi, u16* __restrict__ wv_lo,
                           u16* __restrict__ wq_hi, u16* __restrict__ wq_lo,
                           u16* __restrict__ wo_hi, u16* __restrict__ wo_lo,
                           u16* __restrict__ w1_hi, u16* __restrict__ w1_lo,
                           u16* __restrict__ w2_hi, u16* __restrict__ w2_lo)
{
  int id = blockIdx.x * 256 + threadIdx.x;
  const float* W; u16 *hi, *lo; int Nw, lid;
  if (id < 65536)       { W = Wv; hi = wv_hi; lo = wv_lo; Nw = 256;  lid = id; }
  else if (id < 131072) { W = Wq; hi = wq_hi; lo = wq_lo; Nw = 256;  lid = id - 65536; }
  else if (id < 196608) { W = Wo; hi = wo_hi; lo = wo_lo; Nw = 256;  lid = id - 131072; }
  else if (id < 458752) { W = W1; hi = w1_hi; lo = w1_lo; Nw = 1024; lid = id - 196608; }
  else if (id < 720896) { W = W2; hi = w2_hi; lo = w2_lo; Nw = 256;  lid = id - 458752; }
  else return;
  int k = lid / Nw, n = lid - k * Nw;
  float x = W[lid];
  u16 h = f2bf(x);
  u16 l = f2bf(x - bf2f(h));
  int o = ((k >> 3) * Nw + n) * 8 + (k & 7);
  hi[o] = h; lo[o] = l;
}

// ======================= split-bf16 MFMA GEMM =======================
// C[M x N] = epi( A[M x K] @ W[K x Nw (window wcol0..)] + bias )
// AMODE: 1 add two fp32 (in-kernel split), 2 feat-gather fp32 (in-kernel split),
//        3 bf16 hi-only via global_load_lds (2-term); if A1p!=null it's the SECOND
//          K-half source (dual-buffer hidden, lda both), 4 bf16 hi+lo planes via
//          global_load_lds (3-term, Ap=hi plane, A1p=lo plane; lda in u16 units)
// EPI:   0 +bias -> fp32, 1 +bias,gelu -> bf16 (cols >= ldc go to Cp2 at col-ldc),
//        2 accumulate into fp32 C (no bias)
// Tile 128x128xBK32, 4 waves x (64x64).
template<int AMODE, int EPI>
__global__ __launch_bounds__(256) void mgemm(
    const void* __restrict__ Ap, const void* __restrict__ A1p,
    const u16* __restrict__ Whi, const u16* __restrict__ Wlo,
    const float* __restrict__ bias, void* __restrict__ Cp, void* __restrict__ Cp2,
    int M, int K, int lda, int ldc, int Nw, int wcol0, int ks0,
    const float* __restrict__ f0, const float* __restrict__ f1,
    const float* __restrict__ f2, const float* __restrict__ f3)
{
  constexpr bool GL = (AMODE >= 3);
  constexpr int SMEM_U16 = GL ? (AMODE == AM_SPLIT ? 16384 : 8192) : 8256;
  __shared__ __align__(16) u16 smem[SMEM_U16];
  const int tid  = threadIdx.x;
  const int lane = tid & 63;
  const int w    = tid >> 6;
  const int wr   = w >> 1, wc = w & 1;
  const int row0  = blockIdx.x * 128;
  const int colC0 = blockIdx.y * 128;
  f32x4 acc[4][4] = {};
  const int nk = K >> 5;

  if constexpr (GL) {
    // ---- pre-split bf16 A, async staged, 2-deep double buffer ----
    const u16* Ah = (const u16*)Ap;
    const u16* Al = (const u16*)A1p;
    const int half = nk >> 1;
    auto stage = [&](int t, int buf) {
      const u16* base = Ah; int t2 = t;
      if constexpr (AMODE == AM_HI) {
        if (Al != nullptr && t >= half) { base = Al; t2 = t - half; }
      }
      #pragma unroll
      for (int p = 0; p < 2; ++p) {
        int i = w + p * 4;                       // 8 x 1KB loads, 2 per wave
        int r = row0 + i * 16 + (lane >> 2);
        if (r >= M) r = M - 1;
        size_t goff = (size_t)r * lda + t2 * 32 + (lane & 3) * 8;
        gload16(base + goff, &smem[buf * 4096 + i * 512]);
        if constexpr (AMODE == AM_SPLIT)
          gload16(Al + goff, &smem[8192 + buf * 4096 + i * 512]);
      }
    };
    stage(0, 0);
    __syncthreads();
    for (int kt = 0; kt < nk; ++kt) {
      const int cur = kt & 1;
      if (kt + 1 < nk) stage(kt + 1, cur ^ 1);
      const int slot = lane >> 4;
      const int lrow = lane & 15;
      short8 ah[4], al[4], bh[4], bl[4];
      #pragma unroll
      for (int m = 0; m < 4; ++m) {
        int off = cur * 4096 + (((wr * 64 + m * 16 + lrow) << 2) + slot) * 8;
        ah[m] = *(const short8*)&smem[off];
        if constexpr (AMODE == AM_SPLIT) al[m] = *(const short8*)&smem[8192 + off];
      }
      #pragma unroll
      for (int n = 0; n < 4; ++n) {
        size_t off = ((size_t)((ks0 + kt) * 4 + slot) * Nw + wcol0 + colC0 + wc * 64 + n * 16 + lrow) * 8;
        bh[n] = *(const short8*)(Whi + off);
        bl[n] = *(const short8*)(Wlo + off);
      }
      #pragma unroll
      for (int m = 0; m < 4; ++m)
        #pragma unroll
        for (int n = 0; n < 4; ++n) {
          acc[m][n] = __builtin_amdgcn_mfma_f32_16x16x32_bf16(ah[m], bh[n], acc[m][n], 0, 0, 0);
          acc[m][n] = __builtin_amdgcn_mfma_f32_16x16x32_bf16(ah[m], bl[n], acc[m][n], 0, 0, 0);
          if constexpr (AMODE == AM_SPLIT)
            acc[m][n] = __builtin_amdgcn_mfma_f32_16x16x32_bf16(al[m], bh[n], acc[m][n], 0, 0, 0);
        }
      __syncthreads();
    }
  } else {
    // ---- fp32 A, in-kernel split; padded slot-major layout [slot][row(+pad)][8] ----
    u16* Ahi = smem;
    u16* Alo = smem + 4128;
    for (int kt = 0; kt < nk; ++kt) {
      #pragma unroll
      for (int p = 0; p < 4; ++p) {
        int j = tid + p * 256;
        int row, f4;
        if constexpr (AMODE == AM_FEAT) { f4 = j >> 7; row = j & 127; }
        else                            { row = j >> 3; f4 = j & 7; }
        int gr = row0 + row;
        float4 v = make_float4(0.f, 0.f, 0.f, 0.f);
        if (gr < M) {
          if constexpr (AMODE == AM_FEAT) {
            int b = gr / LV;
            int s = gr - b * LV;
            int l = (s >= 8400) ? 3 : (s >= 8000) ? 2 : (s >= 6400) ? 1 : 0;
            const float* fp = (l == 0) ? f0 : (l == 1) ? f1 : (l == 2) ? f2 : f3;
            const int hw = (l == 0) ? 6400 : (l == 1) ? 1600 : (l == 2) ? 400 : 100;
            const int st = (l == 0) ? 0 : (l == 1) ? 6400 : (l == 2) ? 8000 : 8400;
            const float* base = fp + ((size_t)b * DD + (kt * 32 + f4 * 4)) * hw + (s - st);
            v.x = base[0];
            v.y = base[(size_t)hw];
            v.z = base[2 * (size_t)hw];
            v.w = base[3 * (size_t)hw];
          } else {
            const float* Af = (const float*)Ap;
            v = *(const float4*)(Af + (size_t)gr * lda + kt * 32 + f4 * 4);
            if constexpr (AMODE == AM_ADD) {
              float4 u2 = *(const float4*)((const float*)A1p + (size_t)gr * lda + kt * 32 + f4 * 4);
              v.x += u2.x; v.y += u2.y; v.z += u2.z; v.w += u2.w;
            }
          }
        }
        int slot = f4 >> 1, half2 = f4 & 1;
        int off = (slot * 129 + row) * 8 + half2 * 4;
        u16 h0 = f2bf(v.x), h1 = f2bf(v.y), h2 = f2bf(v.z), h3 = f2bf(v.w);
        uint2 hp; hp.x = (u32)h0 | ((u32)h1 << 16); hp.y = (u32)h2 | ((u32)h3 << 16);
        *(uint2*)&Ahi[off] = hp;
        u16 l0 = f2bf(v.x - bf2f(h0)), l1 = f2bf(v.y - bf2f(h1));
        u16 l2 = f2bf(v.z - bf2f(h2)), l3 = f2bf(v.w - bf2f(h3));
        uint2 lp; lp.x = (u32)l0 | ((u32)l1 << 16); lp.y = (u32)l2 | ((u32)l3 << 16);
        *(uint2*)&Alo[off] = lp;
      }
      __syncthreads();

      const int slot = lane >> 4;
      const int lrow = lane & 15;
      short8 ah[4], al[4], bh[4], bl[4];
      #pragma unroll
      for (int m = 0; m < 4; ++m) {
        int off = (slot * 129 + wr * 64 + m * 16 + lrow) * 8;
        ah[m] = *(const short8*)&Ahi[off];
        al[m] = *(const short8*)&Alo[off];
      }
      #pragma unroll
      for (int n = 0; n < 4; ++n) {
        size_t off = ((size_t)((ks0 + kt) * 4 + slot) * Nw + wcol0 + colC0 + wc * 64 + n * 16 + lrow) * 8;
        bh[n] = *(const short8*)(Whi + off);
        bl[n] = *(const short8*)(Wlo + off);
      }
      #pragma unroll
      for (int m = 0; m < 4; ++m)
        #pragma unroll
        for (int n = 0; n < 4; ++n) {
          acc[m][n] = __builtin_amdgcn_mfma_f32_16x16x32_bf16(ah[m], bh[n], acc[m][n], 0, 0, 0);
          acc[m][n] = __builtin_amdgcn_mfma_f32_16x16x32_bf16(ah[m], bl[n], acc[m][n], 0, 0, 0);
          acc[m][n] = __builtin_amdgcn_mfma_f32_16x16x32_bf16(al[m], bh[n], acc[m][n], 0, 0, 0);
        }
      __syncthreads();
    }
  }

  // epilogue: C/D frag mapping col=lane&15, row=(lane>>4)*4+j  [m89-verified]
  const int lrow = lane & 15;
  #pragma unroll
  for (int m = 0; m < 4; ++m) {
    #pragma unroll
    for (int j = 0; j < 4; ++j) {
      int r = row0 + wr * 64 + m * 16 + ((lane >> 4) << 2) + j;
      if (r >= M) continue;
      #pragma unroll
      for (int n = 0; n < 4; ++n) {
        int c = colC0 + wc * 64 + n * 16 + lrow;
        float v = acc[m][n][j];
        if constexpr (EPI == EP_BIAS) {
          ((float*)Cp)[(size_t)r * ldc + c] = v + bias[c];
        } else if constexpr (EPI == EP_GELU) {
          u16* dst = (u16*)((c < ldc) ? Cp : Cp2);
          dst[(size_t)r * ldc + (c & (ldc - 1))] = f2bf(gelu_f(v + bias[c]));
        } else {
          ((float*)Cp)[(size_t)r * ldc + c] += v;
        }
      }
    }
  }
}

// ======================= LayerNorm kernels =======================
__device__ __forceinline__ float4 ln_core(float4 x, const float* g, const float* bta, int lane) {
  float s  = x.x + x.y + x.z + x.w;
  float s2 = x.x * x.x + x.y * x.y + x.z * x.z + x.w * x.w;
  #pragma unroll
  for (int m = 1; m < 64; m <<= 1) {
    s  += __shfl_xor(s, m);
    s2 += __shfl_xor(s2, m);
  }
  float mean = s * (1.0f / 256.0f);
  float var  = s2 * (1.0f / 256.0f) - mean * mean;
  float rstd = rsqrtf(var + 1e-5f);
  float4 gg = *(const float4*)(g + lane * 4);
  float4 bb = *(const float4*)(bta + lane * 4);
  float4 o;
  o.x = (x.x - mean) * rstd * gg.x + bb.x;
  o.y = (x.y - mean) * rstd * gg.y + bb.y;
  o.z = (x.z - mean) * rstd * gg.z + bb.z;
  o.w = (x.w - mean) * rstd * gg.w + bb.w;
  return o;
}

__global__ void ln_kernel(const float* __restrict__ X, const float* __restrict__ R,
                          const float* __restrict__ g, const float* __restrict__ bta,
                          float* __restrict__ O, int M)
{
  int row  = blockIdx.x * 4 + (threadIdx.x >> 6);
  int lane = threadIdx.x & 63;
  if (row >= M) return;
  size_t base = (size_t)row * DD + lane * 4;
  float4 x = *(const float4*)(X + base);
  float4 r = *(const float4*)(R + base);
  x.x += r.x; x.y += r.y; x.z += r.z; x.w += r.w;
  float4 o = ln_core(x, g, bta, lane);
  *(float4*)(O + base) = o;
}

// LN(X + R) -> split bf16 hi/lo planes
__global__ void ln_vis1(const float* __restrict__ X, const float* __restrict__ R,
                        const float* __restrict__ g, const float* __restrict__ bta,
                        u16* __restrict__ Oh, u16* __restrict__ Ol, int M)
{
  int row  = blockIdx.x * 4 + (threadIdx.x >> 6);
  int lane = threadIdx.x & 63;
  if (row >= M) return;
  size_t base = (size_t)row * DD + lane * 4;
  float4 x = *(const float4*)(X + base);
  float4 r = *(const float4*)(R + base);
  x.x += r.x; x.y += r.y; x.z += r.z; x.w += r.w;
  float4 o = ln_core(x, g, bta, lane);
  u16 h0 = f2bf(o.x), h1 = f2bf(o.y), h2 = f2bf(o.z), h3 = f2bf(o.w);
  uint2 hp; hp.x = (u32)h0 | ((u32)h1 << 16); hp.y = (u32)h2 | ((u32)h3 << 16);
  *(uint2*)(Oh + base) = hp;
  u16 l0 = f2bf(o.x - bf2f(h0)), l1 = f2bf(o.y - bf2f(h1));
  u16 l2 = f2bf(o.z - bf2f(h2)), l3 = f2bf(o.w - bf2f(h3));
  uint2 lp; lp.x = (u32)l0 | ((u32)l1 << 16); lp.y = (u32)l2 | ((u32)l3 << 16);
  *(uint2*)(Ol + base) = lp;
}

// LN(X + (Rh+Rl)) -> fp32 (X may alias O; per-row read-then-write is safe)
__global__ void ln_vis2(const float* __restrict__ X, const u16* __restrict__ Rh,
                        const u16* __restrict__ Rl, const float* __restrict__ g,
                        const float* __restrict__ bta, float* __restrict__ O, int M)
{
  int row  = blockIdx.x * 4 + (threadIdx.x >> 6);
  int lane = threadIdx.x & 63;
  if (row >= M) return;
  size_t base = (size_t)row * DD + lane * 4;
  float4 x = *(const float4*)(X + base);
  uint2 hp = *(const uint2*)(Rh + base);
  uint2 lp = *(const uint2*)(Rl + base);
  x.x += bf2f((u16)hp.x) + bf2f((u16)lp.x);
  x.y += bf2f((u16)(hp.x >> 16)) + bf2f((u16)(lp.x >> 16));
  x.z += bf2f((u16)hp.y) + bf2f((u16)lp.y);
  x.w += bf2f((u16)(hp.y >> 16)) + bf2f((u16)(lp.y >> 16));
  float4 o = ln_core(x, g, bta, lane);
  *(float4*)(O + base) = o;
}

// ======================= deformable softmax+loc =======================
__global__ void softloc_kernel(const float* __restrict__ awl, const float* __restrict__ offb,
                               const float* __restrict__ refp, float* __restrict__ aw,
                               float* __restrict__ loc)
{
  int idx = blockIdx.x * 256 + threadIdx.x;
  if (idx >= BB * LT * NHH) return;
  int h   = idx & 7;
  int row = idx >> 3;
  float v[16]; float mx = -1e30f;
  #pragma unroll
  for (int i = 0; i < 16; ++i) { v[i] = awl[row * 128 + h * 16 + i]; mx = fmaxf(mx, v[i]); }
  float sum = 0.f;
  #pragma unroll
  for (int i = 0; i < 16; ++i) { v[i] = expf(v[i] - mx); sum += v[i]; }
  float inv = 1.0f / sum;
  #pragma unroll
  for (int i = 0; i < 16; ++i) aw[row * 128 + h * 16 + i] = v[i] * inv;
  const float invn[4] = {1.f / 80.f, 1.f / 40.f, 1.f / 20.f, 1.f / 10.f};
  #pragma unroll
  for (int l = 0; l < 4; ++l) {
    float rx = refp[(row * 4 + l) * 2 + 0];
    float ry = refp[(row * 4 + l) * 2 + 1];
    #pragma unroll
    for (int p = 0; p < 4; ++p) {
      int o = row * 256 + h * 32 + l * 8 + p * 2;
      loc[o + 0] = rx + offb[o + 0] * invn[l];
      loc[o + 1] = ry + offb[o + 1] * invn[l];
    }
  }
}

// ======================= deformable sampler =======================
__global__ void sampler_kernel(const float* __restrict__ vproj, const float* __restrict__ loc,
                               const float* __restrict__ aw, float* __restrict__ acc)
{
  int row = blockIdx.x;          // b*32 + q
  int t   = threadIdx.x;
  int h   = t >> 5, hd = t & 31;
  int b   = row >> 5;
  const float* vb = vproj + (size_t)b * LV * DD;
  const int Hs[4] = {80, 40, 20, 10};
  const int st[4] = {0, 6400, 8000, 8400};
  float a = 0.f;
  #pragma unroll
  for (int l = 0; l < 4; ++l) {
    const int Wl = Hs[l], Hl = Hs[l];
    #pragma unroll
    for (int p = 0; p < 4; ++p) {
      int o = row * 256 + h * 32 + l * 8 + p * 2;
      float lx  = loc[o + 0];
      float ly  = loc[o + 1];
      float wgt = aw[row * 128 + h * 16 + l * 4 + p];
      float x = lx * (float)Wl - 0.5f;
      float y = ly * (float)Hl - 0.5f;
      float x0f = floorf(x), y0f = floorf(y);
      float fx = x - x0f, fy = y - y0f;
      int x0 = (int)x0f, y0 = (int)y0f;
      #pragma unroll
      for (int dy = 0; dy < 2; ++dy) {
        #pragma unroll
        for (int dx = 0; dx < 2; ++dx) {
          int xi = x0 + dx, yi = y0 + dy;
          float w2 = (dx ? fx : 1.f - fx) * (dy ? fy : 1.f - fy);
          if (xi >= 0 && xi < Wl && yi >= 0 && yi < Hl) {
            a = fmaf(wgt * w2, vb[(size_t)(st[l] + yi * Wl + xi) * DD + h * 32 + hd], a);
          }
        }
      }
    }
  }
  acc[(size_t)row * DD + t] = a;
}

// ======================= cross attention (32 keys), swizzled LDS =======================
// Block = 512 thr = 16 query rows x 32 lanes; lane l = (head h=l>>2, part p=l&3) owns 8 dims.
// K/V staged in LDS as [key][half q][lane] 16B chunks: lane l's chunk q of key k lives at
// slot (k*2+q)*32 + l == source float4 index k*64 + l*2 + q. A wave-read at fixed (k,q)
// has chunk starts at banks 4*l%32 -> all 8 aligned positions x4 lanes = b128 bank floor.
__global__ __launch_bounds__(512)
void attn_kernel(const float* __restrict__ qh, const float* __restrict__ kh,
                 const float* __restrict__ vh, u16* __restrict__ mo_hi,
                 u16* __restrict__ mo_lo, float* __restrict__ awout)
{
  __shared__ __align__(16) float4 Ks[2048];   // 32 KB
  __shared__ __align__(16) float4 Vs[2048];   // 32 KB
  const int b = blockIdx.y;
  {
    const float4* ksrc = (const float4*)(kh + (size_t)b * 32 * DD);
    const float4* vsrc = (const float4*)(vh + (size_t)b * 32 * DD);
    for (int u = threadIdx.x; u < 2048; u += 512) {
      int k = u >> 6, c = u & 63;
      int slot = (k * 2 + (c & 1)) * 32 + (c >> 1);
      Ks[slot] = ksrc[u];
      Vs[slot] = vsrc[u];
    }
  }
  __syncthreads();

  const int rl = threadIdx.x >> 5;
  const int l  = threadIdx.x & 31;
  const int h  = l >> 2;
  const int part = l & 3;
  const int s  = blockIdx.x * 16 + rl;
  if (s >= LV) return;                 // after staging+sync; no barriers below
  const size_t row = (size_t)b * LV + s;
  const int c0 = h * 32 + part * 8;
  const float scale = 0.17677669529663687f;  // 1/sqrt(32)

  float q[8];
  {
    const float4* qp = (const float4*)(qh + row * DD + c0);
    float4 a = qp[0], c = qp[1];
    q[0]=a.x; q[1]=a.y; q[2]=a.z; q[3]=a.w; q[4]=c.x; q[5]=c.y; q[6]=c.z; q[7]=c.w;
  }

  float sc[32]; float mx = -1e30f;
  #pragma unroll
  for (int k = 0; k < 32; ++k) {
    float4 a = Ks[(k * 2 + 0) * 32 + l];
    float4 c = Ks[(k * 2 + 1) * 32 + l];
    float d = 0.f;
    d = fmaf(q[0], a.x, d); d = fmaf(q[1], a.y, d); d = fmaf(q[2], a.z, d); d = fmaf(q[3], a.w, d);
    d = fmaf(q[4], c.x, d); d = fmaf(q[5], c.y, d); d = fmaf(q[6], c.z, d); d = fmaf(q[7], c.w, d);
    d += __shfl_xor(d, 1);
    d += __shfl_xor(d, 2);
    sc[k] = d * scale;
    mx = fmaxf(mx, sc[k]);
  }
  float sum = 0.f;
  #pragma unroll
  for (int k = 0; k < 32; ++k) { sc[k] = expf(sc[k] - mx); sum += sc[k]; }
  const float inv = 1.0f / sum;
  #pragma unroll
  for (int k = 0; k < 32; ++k) sc[k] *= inv;

  float o[8] = {};
  #pragma unroll
  for (int k = 0; k < 32; ++k) {
    float4 a = Vs[(k * 2 + 0) * 32 + l];
    float4 c = Vs[(k * 2 + 1) * 32 + l];
    const float pk = sc[k];
    o[0] = fmaf(pk, a.x, o[0]); o[1] = fmaf(pk, a.y, o[1]);
    o[2] = fmaf(pk, a.z, o[2]); o[3] = fmaf(pk, a.w, o[3]);
    o[4] = fmaf(pk, c.x, o[4]); o[5] = fmaf(pk, c.y, o[5]);
    o[6] = fmaf(pk, c.z, o[6]); o[7] = fmaf(pk, c.w, o[7]);
  }
  {
    u16 hh[8], ll[8];
    #pragma unroll
    for (int j = 0; j < 8; ++j) {
      hh[j] = f2bf(o[j]);
      ll[j] = f2bf(o[j] - bf2f(hh[j]));
    }
    uint4 hp, lp;
    hp.x = (u32)hh[0] | ((u32)hh[1] << 16); hp.y = (u32)hh[2] | ((u32)hh[3] << 16);
    hp.z = (u32)hh[4] | ((u32)hh[5] << 16); hp.w = (u32)hh[6] | ((u32)hh[7] << 16);
    lp.x = (u32)ll[0] | ((u32)ll[1] << 16); lp.y = (u32)ll[2] | ((u32)ll[3] << 16);
    lp.z = (u32)ll[4] | ((u32)ll[5] << 16); lp.w = (u32)ll[6] | ((u32)ll[7] << 16);
    *(uint4*)(mo_hi + row * DD + c0) = hp;
    *(uint4*)(mo_lo + row * DD + c0) = lp;
  }
  #pragma unroll
  for (int k = 0; k < 32; ++k) {
    float v = sc[k];
    v += __shfl_xor(v, 4);
    v += __shfl_xor(v, 8);
    v += __shfl_xor(v, 16);
    if (h == 0 && (k >> 3) == part) awout[row * 32 + k] = v * 0.125f;
  }
}

extern "C" void kernel_launch(void* const* d_in, const int* in_sizes, int n_in,
                              void* d_out, int out_size, void* d_ws, size_t ws_size,
                              hipStream_t stream)
{
  const float* txt_tokens = (const float*)d_in[0];
  const float* vis_tokens = (const float*)d_in[1];
  const float* feat0 = (const float*)d_in[2];
  const float* feat1 = (const float*)d_in[3];
  const float* feat2 = (const float*)d_in[4];
  const float* feat3 = (const float*)d_in[5];
  const float* refp    = (const float*)d_in[8];
  const float* txt_pos = (const float*)d_in[9];
  const float* vis_pos = (const float*)d_in[10];
  const float* W_off = (const float*)d_in[11]; const float* b_off = (const float*)d_in[12];
  const float* W_aw  = (const float*)d_in[13]; const float* b_aw  = (const float*)d_in[14];
  const float* W_v   = (const float*)d_in[15]; const float* b_v   = (const float*)d_in[16];
  const float* W_do  = (const float*)d_in[17]; const float* b_do  = (const float*)d_in[18];
  const float* W_q   = (const float*)d_in[19]; const float* b_q   = (const float*)d_in[20];
  const float* W_out = (const float*)d_in[21]; const float* b_out = (const float*)d_in[22];
  const float* ln1_g = (const float*)d_in[23]; const float* ln1_b = (const float*)d_in[24];
  const float* ln2_g = (const float*)d_in[25]; const float* ln2_b = (const float*)d_in[26];
  const float* f1W1  = (const float*)d_in[27]; const float* f1b1  = (const float*)d_in[28];
  const float* f1W2  = (const float*)d_in[29]; const float* f1b2  = (const float*)d_in[30];
  const float* Wq_m  = (const float*)d_in[31]; const float* bq_m  = (const float*)d_in[32];
  const float* Wk_m  = (const float*)d_in[33]; const float* bk_m  = (const float*)d_in[34];
  const float* Wv_m  = (const float*)d_in[35]; const float* bv_m  = (const float*)d_in[36];
  const float* Wo_m  = (const float*)d_in[37]; const float* bo_m  = (const float*)d_in[38];
  const float* vln1_g = (const float*)d_in[39]; const float* vln1_b = (const float*)d_in[40];
  const float* vln2_g = (const float*)d_in[41]; const float* vln2_b = (const float*)d_in[42];
  const float* f2W1  = (const float*)d_in[43]; const float* f2b1  = (const float*)d_in[44];
  const float* f2W2  = (const float*)d_in[45]; const float* f2b2  = (const float*)d_in[46];

  const int MV = BB * LV;  // 68000
  float* ws = (float*)d_ws;
  const size_t BIG = (size_t)MV * DD;  // 17,408,000 floats
  float* buf0 = ws;                    // vproj -> moproj out -> ffn2 hidden B
  float* buf1 = ws + BIG;              // qh -> ln1 split planes
  float* buf2 = ws + 2 * BIG;          // mo split planes -> ffn2 hidden A
  float* sm   = ws + 3 * BIG;
  float* qb    = sm;              // 65536
  float* offb  = qb + 65536;
  float* awlb  = offb + 65536;    // 32768
  float* awb   = awlb + 32768;    // 32768
  float* locb  = awb + 32768;     // 65536
  float* accb  = locb + 65536;    // 65536
  float* doutb = accb + 65536;    // 65536
  float* tattn = doutb + 65536;   // 65536
  float* tres1 = tattn + 65536;   // 65536
  float* ffh   = tres1 + 65536;   // 262144
  float* ffb   = ffh + 262144;    // 65536
  float* khb   = ffb + 65536;     // 65536
  float* vhb   = khb + 65536;     // 65536
  // split-weight buffers (u16)
  u16* wsp   = (u16*)(vhb + 65536);
  u16* wv_hi = wsp;               u16* wv_lo = wv_hi + 65536;
  u16* wq_hi = wv_lo + 65536;     u16* wq_lo = wq_hi + 65536;
  u16* wo_hi = wq_lo + 65536;     u16* wo_lo = wo_hi + 65536;
  u16* w1_hi = wo_lo + 65536;     u16* w1_lo = w1_hi + 262144;
  u16* w2_hi = w1_lo + 262144;    u16* w2_lo = w2_hi + 262144;

  // aliased big-buffer views
  u16* mo_hi = (u16*)buf2;  u16* mo_lo = mo_hi + BIG;
  u16* ln_hi = (u16*)buf1;  u16* ln_lo = ln_hi + BIG;
  u16* hidA  = (u16*)buf2;  // ffn2a cols 0-511 (overwrites mo planes, dead by then)
  u16* hidB  = (u16*)buf0;  // ffn2a cols 512-1023 (buf0 free after ln_vis1)

  float* out_txt = (float*)d_out;                       // [8,32,256]
  float* out_vis = out_txt + (size_t)BB * LT * DD;      // [8,8500,256]
  float* out_aw  = out_vis + BIG;                       // [8,8500,32]

  dim3 blk(256);
  #define NOF nullptr, nullptr, nullptr, nullptr

  // ---- weight split prep (single launch) ----
  wsplit_all<<<2816, blk, 0, stream>>>(W_v, Wq_m, Wo_m, f2W1, f2W2,
      wv_hi, wv_lo, wq_hi, wq_lo, wo_hi, wo_lo, w1_hi, w1_lo, w2_hi, w2_lo);

  // ---- big MFMA GEMMs independent of txt chain ----
  mgemm<AM_FEAT, EP_BIAS><<<dim3(532, 2), blk, 0, stream>>>(
      nullptr, nullptr, wv_hi, wv_lo, b_v, buf0, nullptr, MV, DD, DD, DD, DD, 0, 0,
      feat0, feat1, feat2, feat3);
  mgemm<AM_ADD, EP_BIAS><<<dim3(532, 2), blk, 0, stream>>>(
      vis_tokens, vis_pos, wq_hi, wq_lo, bq_m, buf1, nullptr, MV, DD, DD, DD, DD, 0, 0, NOF);

  // ---- txt chain (256 rows, fp32) ----
  gemm_k<32,64,2,4,AM_ADD,EP_BIAS><<<dim3(8,4), blk, 0, stream>>>(
      txt_tokens, txt_pos, W_q, b_q, qb, 256, DD, DD, DD);
  gemm_k<32,64,2,4,AM_PLAIN,EP_BIAS><<<dim3(8,4), blk, 0, stream>>>(
      qb, nullptr, W_off, b_off, offb, 256, DD, DD, DD);
  gemm_k<32,64,2,4,AM_PLAIN,EP_BIAS><<<dim3(8,2), blk, 0, stream>>>(
      qb, nullptr, W_aw, b_aw, awlb, 256, DD, 128, 128);
  softloc_kernel<<<8, blk, 0, stream>>>(awlb, offb, refp, awb, locb);
  sampler_kernel<<<256, blk, 0, stream>>>(buf0, locb, awb, accb);
  gemm_k<32,64,2,4,AM_PLAIN,EP_BIAS><<<dim3(8,4), blk, 0, stream>>>(
      accb, nullptr, W_do, b_do, doutb, 256, DD, DD, DD);
  gemm_k<32,64,2,4,AM_PLAIN,EP_BIAS><<<dim3(8,4), blk, 0, stream>>>(
      doutb, nullptr, W_out, b_out, tattn, 256, DD, DD, DD);
  ln_kernel<<<64, blk, 0, stream>>>(tattn, txt_tokens, ln1_g, ln1_b, tres1, 256);
  gemm_k<32,64,2,4,AM_PLAIN,EP_GELU><<<dim3(8,16), blk, 0, stream>>>(
      tres1, nullptr, f1W1, f1b1, ffh, 256, DD, 1024, 1024);
  gemm_k<32,64,2,4,AM_PLAIN,EP_BIAS><<<dim3(8,4), blk, 0, stream>>>(
      ffh, nullptr, f1W2, f1b2, ffb, 256, 1024, DD, DD);
  ln_kernel<<<64, blk, 0, stream>>>(ffb, tres1, ln2_g, ln2_b, out_txt, 256);

  gemm_k<32,64,2,4,AM_ADD,EP_BIAS><<<dim3(8,4), blk, 0, stream>>>(
      out_txt, txt_pos, Wk_m, bk_m, khb, 256, DD, DD, DD);
  gemm_k<32,64,2,4,AM_ADD,EP_BIAS><<<dim3(8,4), blk, 0, stream>>>(
      out_txt, txt_pos, Wv_m, bv_m, vhb, 256, DD, DD, DD);

  // ---- vli attention + output proj + LN ----
  attn_kernel<<<dim3(532, 8), dim3(512), 0, stream>>>(buf1, khb, vhb, mo_hi, mo_lo, out_aw);
  mgemm<AM_SPLIT, EP_BIAS><<<dim3(532, 2), blk, 0, stream>>>(
      mo_hi, mo_lo, wo_hi, wo_lo, bo_m, buf0, nullptr, MV, DD, 256, DD, DD, 0, 0, NOF);
  ln_vis1<<<17000, blk, 0, stream>>>(buf0, vis_tokens, vln1_g, vln1_b, ln_hi, ln_lo, MV);

  // ---- ffn2: one hidden pass (1024 cols -> hidA/hidB bf16), one K=1024 GEMM ----
  mgemm<AM_SPLIT, EP_GELU><<<dim3(532, 8), blk, 0, stream>>>(
      ln_hi, ln_lo, w1_hi, w1_lo, f2b1, hidA, hidB,
      MV, DD, 256, 512, 1024, 0, 0, NOF);
  mgemm<AM_HI, EP_BIAS><<<dim3(532, 2), blk, 0, stream>>>(
      hidA, hidB, w2_hi, w2_lo, f2b2, out_vis, nullptr,
      MV, 1024, 512, DD, DD, 0, 0, NOF);
  ln_vis2<<<17000, blk, 0, stream>>>(out_vis, ln_hi, ln_lo, vln2_g, vln2_b, out_vis, MV);
  #undef NOF
}

// Round 7
// 1138.085 us; speedup vs baseline: 2.4628x; 1.0392x over previous
//
#include <hip/hip_runtime.h>
#include <cstddef>

// ---- problem constants ----
#define DD   256
#define NHH  8
#define HDD  32
#define BB   8
#define LT   32
#define LV   8500   // 6400+1600+400+100

typedef unsigned short u16;
typedef unsigned int   u32;
typedef __attribute__((ext_vector_type(8))) short short8;
typedef __attribute__((ext_vector_type(8))) unsigned short ushort8;
typedef __attribute__((ext_vector_type(4))) float f32x4;

__device__ __forceinline__ float gelu_f(float x) {
  return 0.5f * x * (1.0f + erff(x * 0.70710678118654752440f));
}

// fp32 -> bf16 round-to-nearest-even
__device__ __forceinline__ u16 f2bf(float x) {
  u32 u = __float_as_uint(x);
  u += 0x7FFFu + ((u >> 16) & 1u);
  return (u16)(u >> 16);
}
__device__ __forceinline__ float bf2f(u16 h) { return __uint_as_float((u32)h << 16); }

// async global->LDS, 16B per lane; LDS dest must be wave-uniform base (+lane*16 implicit)
__device__ __forceinline__ void gload16(const u16* g, u16* l) {
  __builtin_amdgcn_global_load_lds(
      (const __attribute__((address_space(1))) void*)g,
      (__attribute__((address_space(3))) void*)l, 16, 0, 0);
}

enum { AM_PLAIN = 0, AM_ADD = 1, AM_FEAT = 2, AM_HI = 3, AM_SPLIT = 4 };
enum { EP_BIAS = 0, EP_GELU = 1, EP_ACC = 2 };

// ======================= fp32 tiled GEMM (small txt-side only) =======================
template<int BM, int BN, int TM, int TN, int AMODE, int EPI>
__launch_bounds__(256)
__global__ void gemm_k(const float* __restrict__ A0, const float* __restrict__ A1,
                       const float* __restrict__ Wt, const float* __restrict__ bias,
                       float* __restrict__ C, int M, int K, int ldw, int ldc)
{
  constexpr int BK = 16;
  __shared__ __align__(16) float As[BK][BM];
  __shared__ __align__(16) float Ws[BK][BN];
  const int tid  = threadIdx.x;
  const int row0 = blockIdx.x * BM;
  const int col0 = blockIdx.y * BN;
  const int tx = tid % (BN / TN);
  const int ty = tid / (BN / TN);
  float acc[TM][TN] = {};

  for (int k0 = 0; k0 < K; k0 += BK) {
    {
      constexpr int AU = BM * BK / 4;
      for (int u = tid; u < AU; u += 256) {
        int m  = u / (BK / 4);
        int kq = (u % (BK / 4)) * 4;
        int grow = row0 + m;
        float4 v = make_float4(0.f, 0.f, 0.f, 0.f);
        if (grow < M) {
          v = *(const float4*)(A0 + (size_t)grow * K + k0 + kq);
          if constexpr (AMODE == AM_ADD) {
            float4 w = *(const float4*)(A1 + (size_t)grow * K + k0 + kq);
            v.x += w.x; v.y += w.y; v.z += w.z; v.w += w.w;
          }
        }
        As[kq + 0][m] = v.x; As[kq + 1][m] = v.y;
        As[kq + 2][m] = v.z; As[kq + 3][m] = v.w;
      }
    }
    {
      constexpr int WU = BK * BN / 4;
      for (int u = tid; u < WU; u += 256) {
        int k  = u / (BN / 4);
        int n4 = (u % (BN / 4)) * 4;
        *(float4*)&Ws[k][n4] =
            *(const float4*)(Wt + (size_t)(k0 + k) * ldw + col0 + n4);
      }
    }
    __syncthreads();

    #pragma unroll
    for (int k = 0; k < BK; ++k) {
      float a[TM], bv[TN];
      #pragma unroll
      for (int i = 0; i < TM; ++i) a[i] = As[k][ty * TM + i];
      #pragma unroll
      for (int j = 0; j < TN; j += 4) {
        float4 t4 = *(const float4*)&Ws[k][tx * TN + j];
        bv[j] = t4.x; bv[j + 1] = t4.y; bv[j + 2] = t4.z; bv[j + 3] = t4.w;
      }
      #pragma unroll
      for (int i = 0; i < TM; ++i)
        #pragma unroll
        for (int j = 0; j < TN; ++j)
          acc[i][j] = fmaf(a[i], bv[j], acc[i][j]);
    }
    __syncthreads();
  }

  #pragma unroll
  for (int i = 0; i < TM; ++i) {
    int r = row0 + ty * TM + i;
    if (r >= M) continue;
    #pragma unroll
    for (int j4 = 0; j4 < TN; j4 += 4) {
      int c = col0 + tx * TN + j4;
      float4 v = make_float4(acc[i][j4], acc[i][j4 + 1], acc[i][j4 + 2], acc[i][j4 + 3]);
      float4 b4 = *(const float4*)(bias + c);
      v.x += b4.x; v.y += b4.y; v.z += b4.z; v.w += b4.w;
      if constexpr (EPI == EP_GELU) {
        v.x = gelu_f(v.x); v.y = gelu_f(v.y); v.z = gelu_f(v.z); v.w = gelu_f(v.w);
      }
      *(float4*)(C + (size_t)r * ldc + c) = v;
    }
  }
}

// ======================= weight split prep (all 5 weights, one launch) =======================
// out[((k>>3)*Nw + n)*8 + (k&7)] = hi/lo bf16 of W[k][n]  (fragment-ready layout)
__global__ void wsplit_all(const float* __restrict__ Wv, const float* __restrict__ Wq,
                           const float* __restrict__ Wo, const float* __restrict__ W1,
                           const float* __restrict__ W2,
                           u16* __restrict__ wv_hi, u16* __restrict__ wv_lo,
                           u16* __restrict__ wq_hi, u16* __restrict__ wq_lo,
                           u16* __restrict__ wo_hi, u16* __restrict__ wo_lo,
                           u16* __restrict__ w1_hi, u16* __restrict__ w1_lo,
                           u16* __restrict__ w2_hi, u16* __restrict__ w2_lo)
{
  int id = blockIdx.x * 256 + threadIdx.x;
  const float* W; u16 *hi, *lo; int Nw, lid;
  if (id < 65536)       { W = Wv; hi = wv_hi; lo = wv_lo; Nw = 256;  lid = id; }
  else if (id < 131072) { W = Wq; hi = wq_hi; lo = wq_lo; Nw = 256;  lid = id - 65536; }
  else if (id < 196608) { W = Wo; hi = wo_hi; lo = wo_lo; Nw = 256;  lid = id - 131072; }
  else if (id < 458752) { W = W1; hi = w1_hi; lo = w1_lo; Nw = 1024; lid = id - 196608; }
  else if (id < 720896) { W = W2; hi = w2_hi; lo = w2_lo; Nw = 256;  lid = id - 458752; }
  else return;
  int k = lid / Nw, n = lid - k * Nw;
  float x = W[lid];
  u16 h = f2bf(x);
  u16 l = f2bf(x - bf2f(h));
  int o = ((k >> 3) * Nw + n) * 8 + (k & 7);
  hi[o] = h; lo[o] = l;
}

// ======================= split-bf16 MFMA GEMM =======================
// C[M x N] = epi( A[M x K] @ W[K x Nw (window wcol0..)] + bias )
// 1D grid = NRB * NCB blocks, XCD-aware bijective swizzle: all NCB col-blocks of a
// row-panel get the same (b % 8) residue -> same XCD -> A-panel L2 reuse. [T1, ERRATA#11]
// AMODE: 1 add two fp32 (in-kernel split), 2 feat-gather fp32 (in-kernel split),
//        3 bf16 hi-only via global_load_lds (2-term); if A1p!=null it's the SECOND
//          K-half source (dual-buffer hidden, lda both), 4 bf16 hi+lo planes via
//          global_load_lds (3-term, Ap=hi plane, A1p=lo plane; lda in u16 units)
// EPI:   0 +bias -> fp32, 1 +bias,gelu -> bf16 (cols >= ldc go to Cp2 at col-ldc),
//        2 accumulate into fp32 C (no bias)
// Tile 128x128xBK32, 4 waves x (64x64).
template<int AMODE, int EPI, int NCB>
__global__ __launch_bounds__(256) void mgemm(
    const void* __restrict__ Ap, const void* __restrict__ A1p,
    const u16* __restrict__ Whi, const u16* __restrict__ Wlo,
    const float* __restrict__ bias, void* __restrict__ Cp, void* __restrict__ Cp2,
    int M, int K, int lda, int ldc, int Nw, int wcol0, int ks0,
    const float* __restrict__ f0, const float* __restrict__ f1,
    const float* __restrict__ f2, const float* __restrict__ f3)
{
  constexpr bool GL = (AMODE >= 3);
  constexpr int SMEM_U16 = GL ? (AMODE == AM_SPLIT ? 16384 : 8192) : 8256;
  constexpr int LOG2NCB = (NCB == 8) ? 3 : (NCB == 4) ? 2 : (NCB == 2) ? 1 : 0;
  __shared__ __align__(16) u16 smem[SMEM_U16];
  const int tid  = threadIdx.x;
  const int lane = tid & 63;
  const int w    = tid >> 6;
  const int wr   = w >> 1, wc = w & 1;

  // ---- XCD-aware bijective block swizzle ----
  int rb, cb;
  {
    const int b    = blockIdx.x;
    const int nrb  = gridDim.x >> LOG2NCB;
    const int full = nrb & ~7;
    const int thr  = full << LOG2NCB;
    if (b < thr) {
      cb = (b >> 3) & (NCB - 1);
      rb = (b & 7) + 8 * (b >> (3 + LOG2NCB));
    } else {
      const int t = b - thr;
      cb = t & (NCB - 1);
      rb = full + (t >> LOG2NCB);
    }
  }
  const int row0  = rb * 128;
  const int colC0 = cb * 128;
  f32x4 acc[4][4] = {};
  const int nk = K >> 5;

  if constexpr (GL) {
    // ---- pre-split bf16 A, async staged, 2-deep double buffer ----
    const u16* Ah = (const u16*)Ap;
    const u16* Al = (const u16*)A1p;
    const int half = nk >> 1;
    auto stage = [&](int t, int buf) {
      const u16* base = Ah; int t2 = t;
      if constexpr (AMODE == AM_HI) {
        if (Al != nullptr && t >= half) { base = Al; t2 = t - half; }
      }
      #pragma unroll
      for (int p = 0; p < 2; ++p) {
        int i = w + p * 4;                       // 8 x 1KB loads, 2 per wave
        int r = row0 + i * 16 + (lane >> 2);
        if (r >= M) r = M - 1;
        size_t goff = (size_t)r * lda + t2 * 32 + (lane & 3) * 8;
        gload16(base + goff, &smem[buf * 4096 + i * 512]);
        if constexpr (AMODE == AM_SPLIT)
          gload16(Al + goff, &smem[8192 + buf * 4096 + i * 512]);
      }
    };
    stage(0, 0);
    __syncthreads();
    for (int kt = 0; kt < nk; ++kt) {
      const int cur = kt & 1;
      if (kt + 1 < nk) stage(kt + 1, cur ^ 1);
      const int slot = lane >> 4;
      const int lrow = lane & 15;
      short8 ah[4], al[4], bh[4], bl[4];
      #pragma unroll
      for (int m = 0; m < 4; ++m) {
        int off = cur * 4096 + (((wr * 64 + m * 16 + lrow) << 2) + slot) * 8;
        ah[m] = *(const short8*)&smem[off];
        if constexpr (AMODE == AM_SPLIT) al[m] = *(const short8*)&smem[8192 + off];
      }
      #pragma unroll
      for (int n = 0; n < 4; ++n) {
        size_t off = ((size_t)((ks0 + kt) * 4 + slot) * Nw + wcol0 + colC0 + wc * 64 + n * 16 + lrow) * 8;
        bh[n] = *(const short8*)(Whi + off);
        bl[n] = *(const short8*)(Wlo + off);
      }
      #pragma unroll
      for (int m = 0; m < 4; ++m)
        #pragma unroll
        for (int n = 0; n < 4; ++n) {
          acc[m][n] = __builtin_amdgcn_mfma_f32_16x16x32_bf16(ah[m], bh[n], acc[m][n], 0, 0, 0);
          acc[m][n] = __builtin_amdgcn_mfma_f32_16x16x32_bf16(ah[m], bl[n], acc[m][n], 0, 0, 0);
          if constexpr (AMODE == AM_SPLIT)
            acc[m][n] = __builtin_amdgcn_mfma_f32_16x16x32_bf16(al[m], bh[n], acc[m][n], 0, 0, 0);
        }
      __syncthreads();
    }
  } else {
    // ---- fp32 A, in-kernel split; padded slot-major layout [slot][row(+pad)][8] ----
    u16* Ahi = smem;
    u16* Alo = smem + 4128;
    for (int kt = 0; kt < nk; ++kt) {
      #pragma unroll
      for (int p = 0; p < 4; ++p) {
        int j = tid + p * 256;
        int row, f4;
        if constexpr (AMODE == AM_FEAT) { f4 = j >> 7; row = j & 127; }
        else                            { row = j >> 3; f4 = j & 7; }
        int gr = row0 + row;
        float4 v = make_float4(0.f, 0.f, 0.f, 0.f);
        if (gr < M) {
          if constexpr (AMODE == AM_FEAT) {
            int b = gr / LV;
            int s = gr - b * LV;
            int l = (s >= 8400) ? 3 : (s >= 8000) ? 2 : (s >= 6400) ? 1 : 0;
            const float* fp = (l == 0) ? f0 : (l == 1) ? f1 : (l == 2) ? f2 : f3;
            const int hw = (l == 0) ? 6400 : (l == 1) ? 1600 : (l == 2) ? 400 : 100;
            const int st = (l == 0) ? 0 : (l == 1) ? 6400 : (l == 2) ? 8000 : 8400;
            const float* base = fp + ((size_t)b * DD + (kt * 32 + f4 * 4)) * hw + (s - st);
            v.x = base[0];
            v.y = base[(size_t)hw];
            v.z = base[2 * (size_t)hw];
            v.w = base[3 * (size_t)hw];
          } else {
            const float* Af = (const float*)Ap;
            v = *(const float4*)(Af + (size_t)gr * lda + kt * 32 + f4 * 4);
            if constexpr (AMODE == AM_ADD) {
              float4 u2 = *(const float4*)((const float*)A1p + (size_t)gr * lda + kt * 32 + f4 * 4);
              v.x += u2.x; v.y += u2.y; v.z += u2.z; v.w += u2.w;
            }
          }
        }
        int slot = f4 >> 1, half2 = f4 & 1;
        int off = (slot * 129 + row) * 8 + half2 * 4;
        u16 h0 = f2bf(v.x), h1 = f2bf(v.y), h2 = f2bf(v.z), h3 = f2bf(v.w);
        uint2 hp; hp.x = (u32)h0 | ((u32)h1 << 16); hp.y = (u32)h2 | ((u32)h3 << 16);
        *(uint2*)&Ahi[off] = hp;
        u16 l0 = f2bf(v.x - bf2f(h0)), l1 = f2bf(v.y - bf2f(h1));
        u16 l2 = f2bf(v.z - bf2f(h2)), l3 = f2bf(v.w - bf2f(h3));
        uint2 lp; lp.x = (u32)l0 | ((u32)l1 << 16); lp.y = (u32)l2 | ((u32)l3 << 16);
        *(uint2*)&Alo[off] = lp;
      }
      __syncthreads();

      const int slot = lane >> 4;
      const int lrow = lane & 15;
      short8 ah[4], al[4], bh[4], bl[4];
      #pragma unroll
      for (int m = 0; m < 4; ++m) {
        int off = (slot * 129 + wr * 64 + m * 16 + lrow) * 8;
        ah[m] = *(const short8*)&Ahi[off];
        al[m] = *(const short8*)&Alo[off];
      }
      #pragma unroll
      for (int n = 0; n < 4; ++n) {
        size_t off = ((size_t)((ks0 + kt) * 4 + slot) * Nw + wcol0 + colC0 + wc * 64 + n * 16 + lrow) * 8;
        bh[n] = *(const short8*)(Whi + off);
        bl[n] = *(const short8*)(Wlo + off);
      }
      #pragma unroll
      for (int m = 0; m < 4; ++m)
        #pragma unroll
        for (int n = 0; n < 4; ++n) {
          acc[m][n] = __builtin_amdgcn_mfma_f32_16x16x32_bf16(ah[m], bh[n], acc[m][n], 0, 0, 0);
          acc[m][n] = __builtin_amdgcn_mfma_f32_16x16x32_bf16(ah[m], bl[n], acc[m][n], 0, 0, 0);
          acc[m][n] = __builtin_amdgcn_mfma_f32_16x16x32_bf16(al[m], bh[n], acc[m][n], 0, 0, 0);
        }
      __syncthreads();
    }
  }

  // epilogue: C/D frag mapping col=lane&15, row=(lane>>4)*4+j  [m89-verified]
  const int lrow = lane & 15;
  #pragma unroll
  for (int m = 0; m < 4; ++m) {
    #pragma unroll
    for (int j = 0; j < 4; ++j) {
      int r = row0 + wr * 64 + m * 16 + ((lane >> 4) << 2) + j;
      if (r >= M) continue;
      #pragma unroll
      for (int n = 0; n < 4; ++n) {
        int c = colC0 + wc * 64 + n * 16 + lrow;
        float v = acc[m][n][j];
        if constexpr (EPI == EP_BIAS) {
          ((float*)Cp)[(size_t)r * ldc + c] = v + bias[c];
        } else if constexpr (EPI == EP_GELU) {
          u16* dst = (u16*)((c < ldc) ? Cp : Cp2);
          dst[(size_t)r * ldc + (c & (ldc - 1))] = f2bf(gelu_f(v + bias[c]));
        } else {
          ((float*)Cp)[(size_t)r * ldc + c] += v;
        }
      }
    }
  }
}

// ======================= LayerNorm kernels =======================
__device__ __forceinline__ float4 ln_core(float4 x, const float* g, const float* bta, int lane) {
  float s  = x.x + x.y + x.z + x.w;
  float s2 = x.x * x.x + x.y * x.y + x.z * x.z + x.w * x.w;
  #pragma unroll
  for (int m = 1; m < 64; m <<= 1) {
    s  += __shfl_xor(s, m);
    s2 += __shfl_xor(s2, m);
  }
  float mean = s * (1.0f / 256.0f);
  float var  = s2 * (1.0f / 256.0f) - mean * mean;
  float rstd = rsqrtf(var + 1e-5f);
  float4 gg = *(const float4*)(g + lane * 4);
  float4 bb = *(const float4*)(bta + lane * 4);
  float4 o;
  o.x = (x.x - mean) * rstd * gg.x + bb.x;
  o.y = (x.y - mean) * rstd * gg.y + bb.y;
  o.z = (x.z - mean) * rstd * gg.z + bb.z;
  o.w = (x.w - mean) * rstd * gg.w + bb.w;
  return o;
}

__global__ void ln_kernel(const float* __restrict__ X, const float* __restrict__ R,
                          const float* __restrict__ g, const float* __restrict__ bta,
                          float* __restrict__ O, int M)
{
  int row  = blockIdx.x * 4 + (threadIdx.x >> 6);
  int lane = threadIdx.x & 63;
  if (row >= M) return;
  size_t base = (size_t)row * DD + lane * 4;
  float4 x = *(const float4*)(X + base);
  float4 r = *(const float4*)(R + base);
  x.x += r.x; x.y += r.y; x.z += r.z; x.w += r.w;
  float4 o = ln_core(x, g, bta, lane);
  *(float4*)(O + base) = o;
}

// LN(X + R) -> split bf16 hi/lo planes
__global__ void ln_vis1(const float* __restrict__ X, const float* __restrict__ R,
                        const float* __restrict__ g, const float* __restrict__ bta,
                        u16* __restrict__ Oh, u16* __restrict__ Ol, int M)
{
  int row  = blockIdx.x * 4 + (threadIdx.x >> 6);
  int lane = threadIdx.x & 63;
  if (row >= M) return;
  size_t base = (size_t)row * DD + lane * 4;
  float4 x = *(const float4*)(X + base);
  float4 r = *(const float4*)(R + base);
  x.x += r.x; x.y += r.y; x.z += r.z; x.w += r.w;
  float4 o = ln_core(x, g, bta, lane);
  u16 h0 = f2bf(o.x), h1 = f2bf(o.y), h2 = f2bf(o.z), h3 = f2bf(o.w);
  uint2 hp; hp.x = (u32)h0 | ((u32)h1 << 16); hp.y = (u32)h2 | ((u32)h3 << 16);
  *(uint2*)(Oh + base) = hp;
  u16 l0 = f2bf(o.x - bf2f(h0)), l1 = f2bf(o.y - bf2f(h1));
  u16 l2 = f2bf(o.z - bf2f(h2)), l3 = f2bf(o.w - bf2f(h3));
  uint2 lp; lp.x = (u32)l0 | ((u32)l1 << 16); lp.y = (u32)l2 | ((u32)l3 << 16);
  *(uint2*)(Ol + base) = lp;
}

// LN(X + (Rh+Rl)) -> fp32 (X may alias O; per-row read-then-write is safe)
__global__ void ln_vis2(const float* __restrict__ X, const u16* __restrict__ Rh,
                        const u16* __restrict__ Rl, const float* __restrict__ g,
                        const float* __restrict__ bta, float* __restrict__ O, int M)
{
  int row  = blockIdx.x * 4 + (threadIdx.x >> 6);
  int lane = threadIdx.x & 63;
  if (row >= M) return;
  size_t base = (size_t)row * DD + lane * 4;
  float4 x = *(const float4*)(X + base);
  uint2 hp = *(const uint2*)(Rh + base);
  uint2 lp = *(const uint2*)(Rl + base);
  x.x += bf2f((u16)hp.x) + bf2f((u16)lp.x);
  x.y += bf2f((u16)(hp.x >> 16)) + bf2f((u16)(lp.x >> 16));
  x.z += bf2f((u16)hp.y) + bf2f((u16)lp.y);
  x.w += bf2f((u16)(hp.y >> 16)) + bf2f((u16)(lp.y >> 16));
  float4 o = ln_core(x, g, bta, lane);
  *(float4*)(O + base) = o;
}

// ======================= deformable softmax+loc =======================
__global__ void softloc_kernel(const float* __restrict__ awl, const float* __restrict__ offb,
                               const float* __restrict__ refp, float* __restrict__ aw,
                               float* __restrict__ loc)
{
  int idx = blockIdx.x * 256 + threadIdx.x;
  if (idx >= BB * LT * NHH) return;
  int h   = idx & 7;
  int row = idx >> 3;
  float v[16]; float mx = -1e30f;
  #pragma unroll
  for (int i = 0; i < 16; ++i) { v[i] = awl[row * 128 + h * 16 + i]; mx = fmaxf(mx, v[i]); }
  float sum = 0.f;
  #pragma unroll
  for (int i = 0; i < 16; ++i) { v[i] = expf(v[i] - mx); sum += v[i]; }
  float inv = 1.0f / sum;
  #pragma unroll
  for (int i = 0; i < 16; ++i) aw[row * 128 + h * 16 + i] = v[i] * inv;
  const float invn[4] = {1.f / 80.f, 1.f / 40.f, 1.f / 20.f, 1.f / 10.f};
  #pragma unroll
  for (int l = 0; l < 4; ++l) {
    float rx = refp[(row * 4 + l) * 2 + 0];
    float ry = refp[(row * 4 + l) * 2 + 1];
    #pragma unroll
    for (int p = 0; p < 4; ++p) {
      int o = row * 256 + h * 32 + l * 8 + p * 2;
      loc[o + 0] = rx + offb[o + 0] * invn[l];
      loc[o + 1] = ry + offb[o + 1] * invn[l];
    }
  }
}

// ======================= deformable sampler =======================
__global__ void sampler_kernel(const float* __restrict__ vproj, const float* __restrict__ loc,
                               const float* __restrict__ aw, float* __restrict__ acc)
{
  int row = blockIdx.x;          // b*32 + q
  int t   = threadIdx.x;
  int h   = t >> 5, hd = t & 31;
  int b   = row >> 5;
  const float* vb = vproj + (size_t)b * LV * DD;
  const int Hs[4] = {80, 40, 20, 10};
  const int st[4] = {0, 6400, 8000, 8400};
  float a = 0.f;
  #pragma unroll
  for (int l = 0; l < 4; ++l) {
    const int Wl = Hs[l], Hl = Hs[l];
    #pragma unroll
    for (int p = 0; p < 4; ++p) {
      int o = row * 256 + h * 32 + l * 8 + p * 2;
      float lx  = loc[o + 0];
      float ly  = loc[o + 1];
      float wgt = aw[row * 128 + h * 16 + l * 4 + p];
      float x = lx * (float)Wl - 0.5f;
      float y = ly * (float)Hl - 0.5f;
      float x0f = floorf(x), y0f = floorf(y);
      float fx = x - x0f, fy = y - y0f;
      int x0 = (int)x0f, y0 = (int)y0f;
      #pragma unroll
      for (int dy = 0; dy < 2; ++dy) {
        #pragma unroll
        for (int dx = 0; dx < 2; ++dx) {
          int xi = x0 + dx, yi = y0 + dy;
          float w2 = (dx ? fx : 1.f - fx) * (dy ? fy : 1.f - fy);
          if (xi >= 0 && xi < Wl && yi >= 0 && yi < Hl) {
            a = fmaf(wgt * w2, vb[(size_t)(st[l] + yi * Wl + xi) * DD + h * 32 + hd], a);
          }
        }
      }
    }
  }
  acc[(size_t)row * DD + t] = a;
}

// ======================= cross attention (32 keys), swizzled LDS =======================
// Block = 512 thr = 16 query rows x 32 lanes; lane l = (head h=l>>2, part p=l&3) owns 8 dims.
// K/V staged in LDS as [key][half q][lane] 16B chunks -> b128 bank floor.
__global__ __launch_bounds__(512)
void attn_kernel(const float* __restrict__ qh, const float* __restrict__ kh,
                 const float* __restrict__ vh, u16* __restrict__ mo_hi,
                 u16* __restrict__ mo_lo, float* __restrict__ awout)
{
  __shared__ __align__(16) float4 Ks[2048];   // 32 KB
  __shared__ __align__(16) float4 Vs[2048];   // 32 KB
  const int b = blockIdx.y;
  {
    const float4* ksrc = (const float4*)(kh + (size_t)b * 32 * DD);
    const float4* vsrc = (const float4*)(vh + (size_t)b * 32 * DD);
    for (int u = threadIdx.x; u < 2048; u += 512) {
      int k = u >> 6, c = u & 63;
      int slot = (k * 2 + (c & 1)) * 32 + (c >> 1);
      Ks[slot] = ksrc[u];
      Vs[slot] = vsrc[u];
    }
  }
  __syncthreads();

  const int rl = threadIdx.x >> 5;
  const int l  = threadIdx.x & 31;
  const int h  = l >> 2;
  const int part = l & 3;
  const int s  = blockIdx.x * 16 + rl;
  if (s >= LV) return;                 // after staging+sync; no barriers below
  const size_t row = (size_t)b * LV + s;
  const int c0 = h * 32 + part * 8;
  const float scale = 0.17677669529663687f;  // 1/sqrt(32)

  float q[8];
  {
    const float4* qp = (const float4*)(qh + row * DD + c0);
    float4 a = qp[0], c = qp[1];
    q[0]=a.x; q[1]=a.y; q[2]=a.z; q[3]=a.w; q[4]=c.x; q[5]=c.y; q[6]=c.z; q[7]=c.w;
  }

  float sc[32]; float mx = -1e30f;
  #pragma unroll
  for (int k = 0; k < 32; ++k) {
    float4 a = Ks[(k * 2 + 0) * 32 + l];
    float4 c = Ks[(k * 2 + 1) * 32 + l];
    float d = 0.f;
    d = fmaf(q[0], a.x, d); d = fmaf(q[1], a.y, d); d = fmaf(q[2], a.z, d); d = fmaf(q[3], a.w, d);
    d = fmaf(q[4], c.x, d); d = fmaf(q[5], c.y, d); d = fmaf(q[6], c.z, d); d = fmaf(q[7], c.w, d);
    d += __shfl_xor(d, 1);
    d += __shfl_xor(d, 2);
    sc[k] = d * scale;
    mx = fmaxf(mx, sc[k]);
  }
  float sum = 0.f;
  #pragma unroll
  for (int k = 0; k < 32; ++k) { sc[k] = expf(sc[k] - mx); sum += sc[k]; }
  const float inv = 1.0f / sum;
  #pragma unroll
  for (int k = 0; k < 32; ++k) sc[k] *= inv;

  float o[8] = {};
  #pragma unroll
  for (int k = 0; k < 32; ++k) {
    float4 a = Vs[(k * 2 + 0) * 32 + l];
    float4 c = Vs[(k * 2 + 1) * 32 + l];
    const float pk = sc[k];
    o[0] = fmaf(pk, a.x, o[0]); o[1] = fmaf(pk, a.y, o[1]);
    o[2] = fmaf(pk, a.z, o[2]); o[3] = fmaf(pk, a.w, o[3]);
    o[4] = fmaf(pk, c.x, o[4]); o[5] = fmaf(pk, c.y, o[5]);
    o[6] = fmaf(pk, c.z, o[6]); o[7] = fmaf(pk, c.w, o[7]);
  }
  {
    u16 hh[8], ll[8];
    #pragma unroll
    for (int j = 0; j < 8; ++j) {
      hh[j] = f2bf(o[j]);
      ll[j] = f2bf(o[j] - bf2f(hh[j]));
    }
    uint4 hp, lp;
    hp.x = (u32)hh[0] | ((u32)hh[1] << 16); hp.y = (u32)hh[2] | ((u32)hh[3] << 16);
    hp.z = (u32)hh[4] | ((u32)hh[5] << 16); hp.w = (u32)hh[6] | ((u32)hh[7] << 16);
    lp.x = (u32)ll[0] | ((u32)ll[1] << 16); lp.y = (u32)ll[2] | ((u32)ll[3] << 16);
    lp.z = (u32)ll[4] | ((u32)ll[5] << 16); lp.w = (u32)ll[6] | ((u32)ll[7] << 16);
    *(uint4*)(mo_hi + row * DD + c0) = hp;
    *(uint4*)(mo_lo + row * DD + c0) = lp;
  }
  #pragma unroll
  for (int k = 0; k < 32; ++k) {
    float v = sc[k];
    v += __shfl_xor(v, 4);
    v += __shfl_xor(v, 8);
    v += __shfl_xor(v, 16);
    if (h == 0 && (k >> 3) == part) awout[row * 32 + k] = v * 0.125f;
  }
}

extern "C" void kernel_launch(void* const* d_in, const int* in_sizes, int n_in,
                              void* d_out, int out_size, void* d_ws, size_t ws_size,
                              hipStream_t stream)
{
  const float* txt_tokens = (const float*)d_in[0];
  const float* vis_tokens = (const float*)d_in[1];
  const float* feat0 = (const float*)d_in[2];
  const float* feat1 = (const float*)d_in[3];
  const float* feat2 = (const float*)d_in[4];
  const float* feat3 = (const float*)d_in[5];
  const float* refp    = (const float*)d_in[8];
  const float* txt_pos = (const float*)d_in[9];
  const float* vis_pos = (const float*)d_in[10];
  const float* W_off = (const float*)d_in[11]; const float* b_off = (const float*)d_in[12];
  const float* W_aw  = (const float*)d_in[13]; const float* b_aw  = (const float*)d_in[14];
  const float* W_v   = (const float*)d_in[15]; const float* b_v   = (const float*)d_in[16];
  const float* W_do  = (const float*)d_in[17]; const float* b_do  = (const float*)d_in[18];
  const float* W_q   = (const float*)d_in[19]; const float* b_q   = (const float*)d_in[20];
  const float* W_out = (const float*)d_in[21]; const float* b_out = (const float*)d_in[22];
  const float* ln1_g = (const float*)d_in[23]; const float* ln1_b = (const float*)d_in[24];
  const float* ln2_g = (const float*)d_in[25]; const float* ln2_b = (const float*)d_in[26];
  const float* f1W1  = (const float*)d_in[27]; const float* f1b1  = (const float*)d_in[28];
  const float* f1W2  = (const float*)d_in[29]; const float* f1b2  = (const float*)d_in[30];
  const float* Wq_m  = (const float*)d_in[31]; const float* bq_m  = (const float*)d_in[32];
  const float* Wk_m  = (const float*)d_in[33]; const float* bk_m  = (const float*)d_in[34];
  const float* Wv_m  = (const float*)d_in[35]; const float* bv_m  = (const float*)d_in[36];
  const float* Wo_m  = (const float*)d_in[37]; const float* bo_m  = (const float*)d_in[38];
  const float* vln1_g = (const float*)d_in[39]; const float* vln1_b = (const float*)d_in[40];
  const float* vln2_g = (const float*)d_in[41]; const float* vln2_b = (const float*)d_in[42];
  const float* f2W1  = (const float*)d_in[43]; const float* f2b1  = (const float*)d_in[44];
  const float* f2W2  = (const float*)d_in[45]; const float* f2b2  = (const float*)d_in[46];

  const int MV = BB * LV;  // 68000
  float* ws = (float*)d_ws;
  const size_t BIG = (size_t)MV * DD;  // 17,408,000 floats
  float* buf0 = ws;                    // vproj -> moproj out -> ffn2 hidden B
  float* buf1 = ws + BIG;              // qh -> ln1 split planes
  float* buf2 = ws + 2 * BIG;          // mo split planes -> ffn2 hidden A
  float* sm   = ws + 3 * BIG;
  float* qb    = sm;              // 65536
  float* offb  = qb + 65536;
  float* awlb  = offb + 65536;    // 32768
  float* awb   = awlb + 32768;    // 32768
  float* locb  = awb + 32768;     // 65536
  float* accb  = locb + 65536;    // 65536
  float* doutb = accb + 65536;    // 65536
  float* tattn = doutb + 65536;   // 65536
  float* tres1 = tattn + 65536;   // 65536
  float* ffh   = tres1 + 65536;   // 262144
  float* ffb   = ffh + 262144;    // 65536
  float* khb   = ffb + 65536;     // 65536
  float* vhb   = khb + 65536;     // 65536
  // split-weight buffers (u16)
  u16* wsp   = (u16*)(vhb + 65536);
  u16* wv_hi = wsp;               u16* wv_lo = wv_hi + 65536;
  u16* wq_hi = wv_lo + 65536;     u16* wq_lo = wq_hi + 65536;
  u16* wo_hi = wq_lo + 65536;     u16* wo_lo = wo_hi + 65536;
  u16* w1_hi = wo_lo + 65536;     u16* w1_lo = w1_hi + 262144;
  u16* w2_hi = w1_lo + 262144;    u16* w2_lo = w2_hi + 262144;

  // aliased big-buffer views
  u16* mo_hi = (u16*)buf2;  u16* mo_lo = mo_hi + BIG;
  u16* ln_hi = (u16*)buf1;  u16* ln_lo = ln_hi + BIG;
  u16* hidA  = (u16*)buf2;  // ffn2a cols 0-511 (overwrites mo planes, dead by then)
  u16* hidB  = (u16*)buf0;  // ffn2a cols 512-1023 (buf0 free after ln_vis1)

  float* out_txt = (float*)d_out;                       // [8,32,256]
  float* out_vis = out_txt + (size_t)BB * LT * DD;      // [8,8500,256]
  float* out_aw  = out_vis + BIG;                       // [8,8500,32]

  dim3 blk(256);
  #define NOF nullptr, nullptr, nullptr, nullptr

  // ---- weight split prep (single launch) ----
  wsplit_all<<<2816, blk, 0, stream>>>(W_v, Wq_m, Wo_m, f2W1, f2W2,
      wv_hi, wv_lo, wq_hi, wq_lo, wo_hi, wo_lo, w1_hi, w1_lo, w2_hi, w2_lo);

  // ---- big MFMA GEMMs independent of txt chain (1D swizzled grids) ----
  mgemm<AM_FEAT, EP_BIAS, 2><<<1064, blk, 0, stream>>>(
      nullptr, nullptr, wv_hi, wv_lo, b_v, buf0, nullptr, MV, DD, DD, DD, DD, 0, 0,
      feat0, feat1, feat2, feat3);
  mgemm<AM_ADD, EP_BIAS, 2><<<1064, blk, 0, stream>>>(
      vis_tokens, vis_pos, wq_hi, wq_lo, bq_m, buf1, nullptr, MV, DD, DD, DD, DD, 0, 0, NOF);

  // ---- txt chain (256 rows, fp32) ----
  gemm_k<32,64,2,4,AM_ADD,EP_BIAS><<<dim3(8,4), blk, 0, stream>>>(
      txt_tokens, txt_pos, W_q, b_q, qb, 256, DD, DD, DD);
  gemm_k<32,64,2,4,AM_PLAIN,EP_BIAS><<<dim3(8,4), blk, 0, stream>>>(
      qb, nullptr, W_off, b_off, offb, 256, DD, DD, DD);
  gemm_k<32,64,2,4,AM_PLAIN,EP_BIAS><<<dim3(8,2), blk, 0, stream>>>(
      qb, nullptr, W_aw, b_aw, awlb, 256, DD, 128, 128);
  softloc_kernel<<<8, blk, 0, stream>>>(awlb, offb, refp, awb, locb);
  sampler_kernel<<<256, blk, 0, stream>>>(buf0, locb, awb, accb);
  gemm_k<32,64,2,4,AM_PLAIN,EP_BIAS><<<dim3(8,4), blk, 0, stream>>>(
      accb, nullptr, W_do, b_do, doutb, 256, DD, DD, DD);
  gemm_k<32,64,2,4,AM_PLAIN,EP_BIAS><<<dim3(8,4), blk, 0, stream>>>(
      doutb, nullptr, W_out, b_out, tattn, 256, DD, DD, DD);
  ln_kernel<<<64, blk, 0, stream>>>(tattn, txt_tokens, ln1_g, ln1_b, tres1, 256);
  gemm_k<32,64,2,4,AM_PLAIN,EP_GELU><<<dim3(8,16), blk, 0, stream>>>(
      tres1, nullptr, f1W1, f1b1, ffh, 256, DD, 1024, 1024);
  gemm_k<32,64,2,4,AM_PLAIN,EP_BIAS><<<dim3(8,4), blk, 0, stream>>>(
      ffh, nullptr, f1W2, f1b2, ffb, 256, 1024, DD, DD);
  ln_kernel<<<64, blk, 0, stream>>>(ffb, tres1, ln2_g, ln2_b, out_txt, 256);

  gemm_k<32,64,2,4,AM_ADD,EP_BIAS><<<dim3(8,4), blk, 0, stream>>>(
      out_txt, txt_pos, Wk_m, bk_m, khb, 256, DD, DD, DD);
  gemm_k<32,64,2,4,AM_ADD,EP_BIAS><<<dim3(8,4), blk, 0, stream>>>(
      out_txt, txt_pos, Wv_m, bv_m, vhb, 256, DD, DD, DD);

  // ---- vli attention + output proj + LN ----
  attn_kernel<<<dim3(532, 8), dim3(512), 0, stream>>>(buf1, khb, vhb, mo_hi, mo_lo, out_aw);
  mgemm<AM_SPLIT, EP_BIAS, 2><<<1064, blk, 0, stream>>>(
      mo_hi, mo_lo, wo_hi, wo_lo, bo_m, buf0, nullptr, MV, DD, 256, DD, DD, 0, 0, NOF);
  ln_vis1<<<17000, blk, 0, stream>>>(buf0, vis_tokens, vln1_g, vln1_b, ln_hi, ln_lo, MV);

  // ---- ffn2: one hidden pass (1024 cols -> hidA/hidB bf16), one K=1024 GEMM ----
  mgemm<AM_SPLIT, EP_GELU, 8><<<4256, blk, 0, stream>>>(
      ln_hi, ln_lo, w1_hi, w1_lo, f2b1, hidA, hidB,
      MV, DD, 256, 512, 1024, 0, 0, NOF);
  mgemm<AM_HI, EP_BIAS, 2><<<1064, blk, 0, stream>>>(
      hidA, hidB, w2_hi, w2_lo, f2b2, out_vis, nullptr,
      MV, 1024, 512, DD, DD, 0, 0, NOF);
  ln_vis2<<<17000, blk, 0, stream>>>(out_vis, ln_hi, ln_lo, vln2_g, vln2_b, out_vis, MV);
  #undef NOF
}